// Round 10
// baseline (2306.841 us; speedup 1.0000x reference)
//
#include <hip/hip_runtime.h>
#include <cstdint>
#include <cstddef>

#define HID 256

typedef __bf16 bf16;
typedef __bf16 bf16x4 __attribute__((ext_vector_type(4)));
typedef __bf16 bf16x8 __attribute__((ext_vector_type(8)));
typedef float f32x4 __attribute__((ext_vector_type(4)));

// Packed activation layout (per 64-node tile t, 16384 elems):
//   slot ((kt*4 + j)*64 + q*16 + sl)*8  holds node (j*16+sl)'s channels [kt*32+q*8, +8)
// -> a GEMM B-fragment load is 1KB lane-sequential contiguous per wave.

// ---------------- CSR build ----------------

__global__ void k_zero_i32(int* __restrict__ p, int n) {
  int i = blockIdx.x * blockDim.x + threadIdx.x;
  if (i < n) p[i] = 0;
}

__global__ void k_hist(const int* __restrict__ ei, int* __restrict__ deg, int E) {
  int i = blockIdx.x * blockDim.x + threadIdx.x;
  if (i < E) atomicAdd(&deg[ei[E + i]], 1);  // dst = ei[E + i]
}

__global__ void k_scan1(const int* __restrict__ deg, int* __restrict__ offs,
                        int* __restrict__ bsums, int n) {
  __shared__ int sh[1024];
  int i = blockIdx.x * 1024 + threadIdx.x;
  int v = (i < n) ? deg[i] : 0;
  sh[threadIdx.x] = v;
  __syncthreads();
  for (int d = 1; d < 1024; d <<= 1) {
    int t = (threadIdx.x >= (unsigned)d) ? sh[threadIdx.x - d] : 0;
    __syncthreads();
    sh[threadIdx.x] += t;
    __syncthreads();
  }
  if (i < n) offs[i] = sh[threadIdx.x] - v;  // exclusive within block
  if (threadIdx.x == 1023) bsums[blockIdx.x] = sh[1023];
}

__global__ void k_scan2(int* __restrict__ bsums, int nb) {
  if (threadIdx.x == 0 && blockIdx.x == 0) {
    int run = 0;
    for (int b = 0; b < nb; ++b) { int t = bsums[b]; bsums[b] = run; run += t; }
  }
}

__global__ void k_scan3(int* __restrict__ offs, int* __restrict__ cursor,
                        const int* __restrict__ bsums, int n, int E) {
  int i = blockIdx.x * 1024 + threadIdx.x;
  if (i < n) { int o = offs[i] + bsums[blockIdx.x]; offs[i] = o; cursor[i] = o; }
  if (i == 0) offs[n] = E;
}

// fill CSR sorted by dst; also record dst and original edge id per slot
__global__ void k_fill(const int* __restrict__ ei, int* __restrict__ cursor,
                       int* __restrict__ csr, int* __restrict__ edst,
                       int* __restrict__ eperm, int E) {
  int i = blockIdx.x * blockDim.x + threadIdx.x;
  if (i < E) {
    int s = ei[i], d = ei[E + i];
    int pos = atomicAdd(&cursor[d], 1);
    csr[pos] = s;
    edst[pos] = d;
    eperm[pos] = i;
  }
}

// ---------------- fragment-pack weights ----------------
// P[mat][tile][kt][lane][8]: lane holds W[tile*16 + (lane&15)][kt*32 + (lane>>4)*8 + j]

__global__ void k_pack(const float* __restrict__ W, bf16* __restrict__ P,
                       int OUT, int K, int count) {
  int g = blockIdx.x * blockDim.x + threadIdx.x;
  int total = count * OUT * (K >> 3);
  if (g >= total) return;
  int lane = g & 63;
  int rest = g >> 6;
  int KT = K >> 5;
  int kt = rest % KT;
  int rest2 = rest / KT;
  int OT = OUT >> 4;
  int tile = rest2 % OT;
  int mat = rest2 / OT;
  const float* src = W + (size_t)mat * OUT * K +
                     (size_t)(tile * 16 + (lane & 15)) * K + kt * 32 + (lane >> 4) * 8;
  bf16* dst = P + (size_t)g * 8;
#pragma unroll
  for (int j = 0; j < 8; ++j) dst[j] = (bf16)src[j];
}

// ---------------- input fc: writes row-major hb AND packed hbp ----------------

__global__ __launch_bounds__(256) void k_input_fc(
    const float* __restrict__ x, const float* __restrict__ Win,
    bf16* __restrict__ hb, bf16* __restrict__ hbp,
    float* __restrict__ sums0, int N) {
  if (blockIdx.x == 0) { sums0[threadIdx.x] = 0.f; sums0[256 + threadIdx.x] = 0.f; }
  int gid = blockIdx.x * blockDim.x + threadIdx.x;
  int total = N * 32;  // 16B chunks
  int stride = gridDim.x * blockDim.x;
  for (int idx = gid; idx < total; idx += stride) {
    int node = idx >> 5, c8 = idx & 31;
    float xa = x[2 * node], xb = x[2 * node + 1];
    bf16x8 o;
#pragma unroll
    for (int k = 0; k < 8; ++k) {
      int c = c8 * 8 + k;
      o[k] = (bf16)(xa * Win[2 * c] + xb * Win[2 * c + 1]);
    }
    *(bf16x8*)(hb + (size_t)node * HID + c8 * 8) = o;
    int t = node >> 6, vi = node & 63;
    int jj = vi >> 4, sl = vi & 15, kt = c8 >> 2, q = c8 & 3;
    *(bf16x8*)(hbp + (size_t)t * 16384 + ((kt * 4 + jj) * 64 + q * 16 + sl) * 8) = o;
  }
}

// ---------------- aggregation: gathers row-major hb, writes PACKED aggp ----------------

__global__ __launch_bounds__(256) void k_aggregate(
    const bf16* __restrict__ hb, const int* __restrict__ offs,
    const int* __restrict__ csr, bf16* __restrict__ aggp, int N) {
  int gwave = (int)((blockIdx.x * blockDim.x + threadIdx.x) >> 6);
  int lane = threadIdx.x & 63;
  int node = gwave * 2 + (lane >> 5);
  int l32 = lane & 31;
  if (node >= N) return;
  int e0 = offs[node], e1 = offs[node + 1];
  float a[8] = {};
  int e = e0;
  for (; e + 3 < e1; e += 4) {  // 4 independent 16B gathers in flight
    int s0 = csr[e], s1 = csr[e + 1], s2 = csr[e + 2], s3 = csr[e + 3];
    bf16x8 v0 = *(const bf16x8*)(hb + (size_t)s0 * HID + l32 * 8);
    bf16x8 v1 = *(const bf16x8*)(hb + (size_t)s1 * HID + l32 * 8);
    bf16x8 v2 = *(const bf16x8*)(hb + (size_t)s2 * HID + l32 * 8);
    bf16x8 v3 = *(const bf16x8*)(hb + (size_t)s3 * HID + l32 * 8);
#pragma unroll
    for (int k = 0; k < 8; ++k)
      a[k] += ((float)v0[k] + (float)v1[k]) + ((float)v2[k] + (float)v3[k]);
  }
  for (; e < e1; ++e) {
    int s0 = csr[e];
    bf16x8 v0 = *(const bf16x8*)(hb + (size_t)s0 * HID + l32 * 8);
#pragma unroll
    for (int k = 0; k < 8; ++k) a[k] += (float)v0[k];
  }
  bf16x8 o;
#pragma unroll
  for (int k = 0; k < 8; ++k) o[k] = (bf16)a[k];
  int t = node >> 6, vi = node & 63;
  int jj = vi >> 4, sl = vi & 15, kt = l32 >> 2, q = l32 & 3;
  *(bf16x8*)(aggp + (size_t)t * 16384 + ((kt * 4 + jj) * 64 + q * 16 + sl) * 8) = o;
}

// ---------------- layer GEMM: zero-LDS, barrier-free main loop ----------------
// Block = 64 nodes x 256 ch, operand-swapped MFMA D[ch][node]. B-fragments are
// direct lane-sequential global loads from packed aggp/hbp; A-fragments stream
// from packed weights (L2-hot). Only LDS: 2KB BN-stat reduce.

__global__ __launch_bounds__(256) void k_layer_gemm(
    const bf16* __restrict__ aggp, const bf16* __restrict__ hbp,
    const bf16* __restrict__ Pr, const bf16* __restrict__ Po,
    const float* __restrict__ bias, bf16* __restrict__ out,
    float* __restrict__ sums, int N) {
  __shared__ float bsum[256], bsq[256];
  int tid = threadIdx.x;
  int wave = tid >> 6, lane = tid & 63;
  int l15 = lane & 15, lq = lane >> 4;
  int m0 = blockIdx.x * 64;
  size_t tb = (size_t)blockIdx.x * 16384;
  f32x4 acc[4][4] = {};
  const bf16* PrW = Pr + (size_t)wave * 4 * 8 * 64 * 8;
  const bf16* PoW = Po + (size_t)wave * 4 * 8 * 64 * 8;

  for (int phase = 0; phase < 2; ++phase) {
    const bf16* src = (phase ? hbp : aggp) + tb;
    const bf16* PW = phase ? PoW : PrW;
    for (int kt = 0; kt < 8; ++kt) {
      bf16x8 bfr[4];
#pragma unroll
      for (int j = 0; j < 4; ++j)
        bfr[j] = *(const bf16x8*)(src + ((kt * 4 + j) * 64 + lane) * 8);
#pragma unroll
      for (int i = 0; i < 4; ++i) {
        bf16x8 afr = *(const bf16x8*)(PW + ((size_t)(i * 8 + kt) * 64 + lane) * 8);
#pragma unroll
        for (int j = 0; j < 4; ++j)
          acc[i][j] = __builtin_amdgcn_mfma_f32_16x16x32_bf16(afr, bfr[j], acc[i][j], 0, 0, 0);
      }
    }
  }

  // epilogue: bias, 8B row-major stores, BN stats (in-lane j-sum + l15 butterfly)
  f32x4 bv[4];
#pragma unroll
  for (int i = 0; i < 4; ++i)
    bv[i] = *(const f32x4*)(bias + wave * 64 + i * 16 + lq * 4);
  float s[4][4] = {}, q[4][4] = {};
#pragma unroll
  for (int j = 0; j < 4; ++j) {
    int gn = m0 + j * 16 + l15;
    bool ok = gn < N;
#pragma unroll
    for (int i = 0; i < 4; ++i) {
      bf16x4 o;
#pragma unroll
      for (int r = 0; r < 4; ++r) {
        float v = acc[i][j][r] + bv[i][r];
        o[r] = (bf16)v;
        if (ok) { s[i][r] += v; q[i][r] += v * v; }
      }
      if (ok) *(bf16x4*)(out + (size_t)gn * HID + wave * 64 + i * 16 + lq * 4) = o;
    }
  }
#pragma unroll
  for (int d = 1; d < 16; d <<= 1) {
#pragma unroll
    for (int i = 0; i < 4; ++i)
#pragma unroll
      for (int r = 0; r < 4; ++r) {
        s[i][r] += __shfl_xor(s[i][r], d, 64);
        q[i][r] += __shfl_xor(q[i][r], d, 64);
      }
  }
  if (l15 == 0) {
#pragma unroll
    for (int i = 0; i < 4; ++i)
#pragma unroll
      for (int r = 0; r < 4; ++r) {
        bsum[wave * 64 + i * 16 + lq * 4 + r] = s[i][r];
        bsq[wave * 64 + i * 16 + lq * 4 + r] = q[i][r];
      }
  }
  __syncthreads();
  atomicAdd(&sums[tid], bsum[tid]);
  atomicAdd(&sums[256 + tid], bsq[tid]);
}

// ---------------- BN finalize + ReLU + residual (bf16 h; writes hb AND hbp) --------

__global__ __launch_bounds__(256) void k_bn_residual(
    const bf16* __restrict__ outb, bf16* __restrict__ hb, bf16* __restrict__ hbp,
    const float* __restrict__ sums, float* __restrict__ zsums,
    const float* __restrict__ gamma, const float* __restrict__ beta,
    int N, float invN) {
  int t = threadIdx.x;
  if (blockIdx.x == 0) { zsums[t] = 0.f; zsums[256 + t] = 0.f; }
  int c8 = t & 31;
  int cg = c8 * 8;
  int kt = c8 >> 2, q = c8 & 3;
  int r0 = blockIdx.x * 32 + (t >> 5) * 4;
  float a[8], b[8];
#pragma unroll
  for (int k = 0; k < 8; ++k) {
    int c = cg + k;
    float mean = sums[c] * invN;
    float var = sums[256 + c] * invN - mean * mean;
    float istd = rsqrtf(var + 1e-5f);
    a[k] = istd * gamma[c];
    b[k] = fmaf(-mean, a[k], beta[c]);
  }
  int r1 = min(r0 + 4, N);
  for (int r = r0; r < r1; ++r) {
    size_t idx = (size_t)r * HID + cg;
    bf16x8 ov = *(const bf16x8*)(outb + idx);
    bf16x8 hv = *(const bf16x8*)(hb + idx);
    bf16x8 o;
#pragma unroll
    for (int k = 0; k < 8; ++k) {
      float y = fmaf((float)ov[k], a[k], b[k]);
      y = fmaxf(y, 0.f);
      o[k] = (bf16)((float)hv[k] + y);
    }
    *(bf16x8*)(hb + idx) = o;
    int tt = r >> 6, vi = r & 63;
    int jj = vi >> 4, sl = vi & 15;
    *(bf16x8*)(hbp + (size_t)tt * 16384 + ((kt * 4 + jj) * 64 + q * 16 + sl) * 8) = o;
  }
}

// ---------------- fused edge MLP, dst-sorted edge order ----------------
// Edges processed in CSR (dst-sorted) order: src = csr[pos], dst = edst[pos];
// dst rows per block collapse to ~7 contiguous nodes (L1/L2-local). Output
// scattered to original order via eperm. Structure otherwise = proven R9 variant.

__global__ __launch_bounds__(256) void k_edge_mlp(
    const bf16* __restrict__ hb, const int* __restrict__ csr,
    const int* __restrict__ edst, const int* __restrict__ eperm,
    const bf16* __restrict__ P1, const float* __restrict__ b1v,
    const bf16* __restrict__ P2, const float* __restrict__ b2v,
    const float* __restrict__ w3, const float* __restrict__ b3,
    float* __restrict__ outp, int E) {
  __shared__ __align__(16) bf16 asp[4 * 64 * 8];   // 4KB packed staging
  __shared__ __align__(16) bf16 z1f[32 * 64 * 8];  // 32KB packed z1
  __shared__ int nd[128];   // [0..63]=src, [64..127]=dst (sorted order)
  __shared__ int oidx[64];  // original edge id (scatter target), -1 = inactive
  __shared__ float red[64];
  int tid = threadIdx.x;
  int e0 = blockIdx.x * 64;
  if (tid < 64) {
    int p = e0 + tid;
    nd[tid] = (p < E) ? csr[p] : 0;
    oidx[tid] = (p < E) ? eperm[p] : -1;
  } else if (tid < 128) {
    int p = e0 + (tid - 64);
    nd[tid] = (p < E) ? edst[p] : 0;
  }
  if (tid < 64) red[tid] = 0.f;
  __syncthreads();
  int wave = tid >> 6, lane = tid & 63;
  int l15 = lane & 15, lq = lane >> 4;
  int sr = tid >> 2, sq = tid & 3;

  // ---- GEMM1: D[c1][e] = W1 . cat^T, K=512 ----
  f32x4 acc[4][4] = {};
  const bf16* P1W = P1 + (size_t)wave * 4 * 16 * 64 * 8;
  for (int ks = 0; ks < 16; ++ks) {
    {
      int node = nd[(ks >> 3) * 64 + sr];
      bf16x8 v = *(const bf16x8*)(hb + (size_t)node * HID + (ks & 7) * 32 + sq * 8);
      *(bf16x8*)(&asp[((sr >> 4) * 64 + sq * 16 + (sr & 15)) * 8]) = v;
    }
    __syncthreads();
    bf16x8 bfr[4];
#pragma unroll
    for (int j = 0; j < 4; ++j)
      bfr[j] = *(const bf16x8*)(&asp[(j * 64 + lane) * 8]);  // lane-sequential
#pragma unroll
    for (int i = 0; i < 4; ++i) {
      bf16x8 wf = *(const bf16x8*)(P1W + ((size_t)(i * 16 + ks) * 64 + lane) * 8);
#pragma unroll
      for (int j = 0; j < 4; ++j)
        acc[i][j] = __builtin_amdgcn_mfma_f32_16x16x32_bf16(wf, bfr[j], acc[i][j], 0, 0, 0);
    }
    __syncthreads();
  }
  // z1 -> fragment-packed LDS (8B writes, benign 2-way alias)
  {
    f32x4 b1i[4];
#pragma unroll
    for (int i = 0; i < 4; ++i)
      b1i[i] = *(const f32x4*)(b1v + wave * 64 + i * 16 + lq * 4);
#pragma unroll
    for (int j = 0; j < 4; ++j) {
#pragma unroll
      for (int i = 0; i < 4; ++i) {
        bf16x4 o;
#pragma unroll
        for (int r = 0; r < 4; ++r)
          o[r] = (bf16)fmaxf(acc[i][j][r] + b1i[i][r], 0.f);
        int kt = wave * 2 + (i >> 1);
        int slot = l15 + 16 * ((i & 1) * 2 + (lq >> 1));
        *(bf16x4*)(&z1f[((j * 8 + kt) * 64 + slot) * 8 + (lq & 1) * 4]) = o;
      }
    }
  }
  __syncthreads();

  // ---- GEMM2: D[c2][e] = W2 . z1^T, K=256 ----
  f32x4 acc2[4][4] = {};
  const bf16* P2W = P2 + (size_t)wave * 4 * 8 * 64 * 8;
  for (int ks = 0; ks < 8; ++ks) {
    bf16x8 zf[4];
#pragma unroll
    for (int j = 0; j < 4; ++j)
      zf[j] = *(const bf16x8*)(&z1f[((j * 8 + ks) * 64 + lane) * 8]);
#pragma unroll
    for (int i = 0; i < 4; ++i) {
      bf16x8 wf = *(const bf16x8*)(P2W + ((size_t)(i * 8 + ks) * 64 + lane) * 8);
#pragma unroll
      for (int j = 0; j < 4; ++j)
        acc2[i][j] = __builtin_amdgcn_mfma_f32_16x16x32_bf16(wf, zf[j], acc2[i][j], 0, 0, 0);
    }
  }

  // ---- logit = relu(z2).w3 from registers; lane col = e ----
  f32x4 b2i[4], w3i[4];
#pragma unroll
  for (int i = 0; i < 4; ++i) {
    b2i[i] = *(const f32x4*)(b2v + wave * 64 + i * 16 + lq * 4);
    w3i[i] = *(const f32x4*)(w3 + wave * 64 + i * 16 + lq * 4);
  }
  float sj2[4] = {};
#pragma unroll
  for (int j = 0; j < 4; ++j)
#pragma unroll
    for (int i = 0; i < 4; ++i)
#pragma unroll
      for (int r = 0; r < 4; ++r)
        sj2[j] = fmaf(fmaxf(acc2[i][j][r] + b2i[i][r], 0.f), w3i[i][r], sj2[j]);
#pragma unroll
  for (int j = 0; j < 4; ++j) {
    sj2[j] += __shfl_xor(sj2[j], 16, 64);
    sj2[j] += __shfl_xor(sj2[j], 32, 64);
  }
  if (lq == 0) {
#pragma unroll
    for (int j = 0; j < 4; ++j)
      atomicAdd(&red[j * 16 + l15], sj2[j]);
  }
  __syncthreads();
  if (tid < 64) {
    int oi = oidx[tid];
    if (oi >= 0) {
      float logit = red[tid] + b3[0];
      outp[oi] = 1.f / (1.f + expf(-logit));
    }
  }
}

// ---------------- host ----------------

static inline size_t align256(size_t x) { return (x + 255) & ~(size_t)255; }

extern "C" void kernel_launch(void* const* d_in, const int* in_sizes, int n_in,
                              void* d_out, int out_size, void* d_ws, size_t ws_size,
                              hipStream_t stream) {
  const float* x     = (const float*)d_in[0];
  const int*   ei    = (const int*)d_in[1];
  const float* Win   = (const float*)d_in[2];
  const float* Wrel  = (const float*)d_in[3];
  const float* brel  = (const float*)d_in[4];
  const float* Wroot = (const float*)d_in[5];
  const float* gamma = (const float*)d_in[6];
  const float* beta  = (const float*)d_in[7];
  const float* W1    = (const float*)d_in[8];
  const float* b1    = (const float*)d_in[9];
  const float* W2    = (const float*)d_in[10];
  const float* b2    = (const float*)d_in[11];
  const float* W3    = (const float*)d_in[12];
  const float* b3    = (const float*)d_in[13];

  const int N = in_sizes[0] / 2;              // 50000
  const int E = in_sizes[1] / 2;              // 500000
  const int L = in_sizes[3] / (HID * HID);    // 15
  const int NT = (N + 63) / 64;               // node tiles

  char* p = (char*)d_ws;
  auto alloc = [&](size_t bytes) { char* r = p; p += align256(bytes); return r; };
  bf16*  hb    = (bf16*)alloc((size_t)N * HID * 2);
  bf16*  hbp   = (bf16*)alloc((size_t)NT * 16384 * 2);
  bf16*  aggp  = (bf16*)alloc((size_t)NT * 16384 * 2);
  bf16*  outb  = (bf16*)alloc((size_t)N * HID * 2);
  bf16*  Prel  = (bf16*)alloc((size_t)L * HID * HID * 2);
  bf16*  Proot = (bf16*)alloc((size_t)L * HID * HID * 2);
  bf16*  P1    = (bf16*)alloc((size_t)HID * 2 * HID * 2);
  bf16*  P2    = (bf16*)alloc((size_t)HID * HID * 2);
  int*   deg   = (int*)alloc((size_t)N * 4);
  int*   offs  = (int*)alloc((size_t)(N + 1) * 4);
  int*   cursor= (int*)alloc((size_t)N * 4);
  int*   csr   = (int*)alloc((size_t)E * 4);
  int*   edst  = (int*)alloc((size_t)E * 4);
  int*   eperm = (int*)alloc((size_t)E * 4);
  int*   bsums = (int*)alloc(64 * 4);
  float* sums  = (float*)alloc(1024 * 4);  // two ping-pong buffers of 512
  (void)ws_size; (void)n_in; (void)out_size;

  const int nb = (N + 1023) / 1024;

  // CSR build (dst-sorted edge order)
  k_zero_i32<<<(N + 255) / 256, 256, 0, stream>>>(deg, N);
  k_hist<<<(E + 255) / 256, 256, 0, stream>>>(ei, deg, E);
  k_scan1<<<nb, 1024, 0, stream>>>(deg, offs, bsums, N);
  k_scan2<<<1, 64, 0, stream>>>(bsums, nb);
  k_scan3<<<nb, 1024, 0, stream>>>(offs, cursor, bsums, N, E);
  k_fill<<<(E + 255) / 256, 256, 0, stream>>>(ei, cursor, csr, edst, eperm, E);

  // fragment-pack weights
  {
    int g1 = L * HID * HID / 8;
    k_pack<<<(g1 + 255) / 256, 256, 0, stream>>>(Wrel, Prel, HID, HID, L);
    k_pack<<<(g1 + 255) / 256, 256, 0, stream>>>(Wroot, Proot, HID, HID, L);
    int g2 = HID * 2 * HID / 8;
    k_pack<<<(g2 + 255) / 256, 256, 0, stream>>>(W1, P1, HID, 2 * HID, 1);
    int g3 = HID * HID / 8;
    k_pack<<<(g3 + 255) / 256, 256, 0, stream>>>(W2, P2, HID, HID, 1);
  }

  // input fc: hb + hbp (+ zero sums buffer 0)
  k_input_fc<<<1024, 256, 0, stream>>>(x, Win, hb, hbp, sums, N);

  // layers: aggregate(packed) -> zero-LDS GEMM(+stats) -> BN+ReLU+residual
  const float invN = 1.0f / (float)N;
  for (int l = 0; l < L; ++l) {
    int sel = l & 1;
    k_aggregate<<<(N + 7) / 8, 256, 0, stream>>>(hb, offs, csr, aggp, N);
    k_layer_gemm<<<NT, 256, 0, stream>>>(
        aggp, hbp, Prel + (size_t)l * HID * HID, Proot + (size_t)l * HID * HID,
        brel + (size_t)l * HID, outb, sums + sel * 512, N);
    k_bn_residual<<<(N + 31) / 32, 256, 0, stream>>>(
        outb, hb, hbp, sums + sel * 512, sums + (1 - sel) * 512,
        gamma + (size_t)l * HID, beta + (size_t)l * HID, N, invN);
  }

  // edge MLP (dst-sorted order, scatter output)
  k_edge_mlp<<<(E + 63) / 64, 256, 0, stream>>>(
      hb, csr, edst, eperm, P1, b1, P2, b2, W3, b3, (float*)d_out, E);
}

// Round 11
// 2013.256 us; speedup vs baseline: 1.1458x; 1.1458x over previous
//
#include <hip/hip_runtime.h>
#include <cstdint>
#include <cstddef>

#define HID 256

typedef __bf16 bf16;
typedef __bf16 bf16x4 __attribute__((ext_vector_type(4)));
typedef __bf16 bf16x8 __attribute__((ext_vector_type(8)));
typedef float f32x4 __attribute__((ext_vector_type(4)));

// ---------------- CSR build ----------------

__global__ void k_zero_i32(int* __restrict__ p, int n) {
  int i = blockIdx.x * blockDim.x + threadIdx.x;
  if (i < n) p[i] = 0;
}

__global__ void k_hist(const int* __restrict__ ei, int* __restrict__ deg, int E) {
  int i = blockIdx.x * blockDim.x + threadIdx.x;
  if (i < E) atomicAdd(&deg[ei[E + i]], 1);  // dst = ei[E + i]
}

__global__ void k_scan1(const int* __restrict__ deg, int* __restrict__ offs,
                        int* __restrict__ bsums, int n) {
  __shared__ int sh[1024];
  int i = blockIdx.x * 1024 + threadIdx.x;
  int v = (i < n) ? deg[i] : 0;
  sh[threadIdx.x] = v;
  __syncthreads();
  for (int d = 1; d < 1024; d <<= 1) {
    int t = (threadIdx.x >= (unsigned)d) ? sh[threadIdx.x - d] : 0;
    __syncthreads();
    sh[threadIdx.x] += t;
    __syncthreads();
  }
  if (i < n) offs[i] = sh[threadIdx.x] - v;  // exclusive within block
  if (threadIdx.x == 1023) bsums[blockIdx.x] = sh[1023];
}

__global__ void k_scan2(int* __restrict__ bsums, int nb) {
  if (threadIdx.x == 0 && blockIdx.x == 0) {
    int run = 0;
    for (int b = 0; b < nb; ++b) { int t = bsums[b]; bsums[b] = run; run += t; }
  }
}

__global__ void k_scan3(int* __restrict__ offs, int* __restrict__ cursor,
                        const int* __restrict__ bsums, int n, int E) {
  int i = blockIdx.x * 1024 + threadIdx.x;
  if (i < n) { int o = offs[i] + bsums[blockIdx.x]; offs[i] = o; cursor[i] = o; }
  if (i == 0) offs[n] = E;
}

// fill CSR sorted by dst; also record dst and original edge id per slot
__global__ void k_fill(const int* __restrict__ ei, int* __restrict__ cursor,
                       int* __restrict__ csr, int* __restrict__ edst,
                       int* __restrict__ eperm, int E) {
  int i = blockIdx.x * blockDim.x + threadIdx.x;
  if (i < E) {
    int s = ei[i], d = ei[E + i];
    int pos = atomicAdd(&cursor[d], 1);
    csr[pos] = s;
    edst[pos] = d;
    eperm[pos] = i;
  }
}

// ---------------- fragment-pack weights ----------------
// P[mat][tile][kt][lane][8]: lane holds W[tile*16 + (lane&15)][kt*32 + (lane>>4)*8 + j]

__global__ void k_pack(const float* __restrict__ W, bf16* __restrict__ P,
                       int OUT, int K, int count) {
  int g = blockIdx.x * blockDim.x + threadIdx.x;
  int total = count * OUT * (K >> 3);
  if (g >= total) return;
  int lane = g & 63;
  int rest = g >> 6;
  int KT = K >> 5;
  int kt = rest % KT;
  int rest2 = rest / KT;
  int OT = OUT >> 4;
  int tile = rest2 % OT;
  int mat = rest2 / OT;
  const float* src = W + (size_t)mat * OUT * K +
                     (size_t)(tile * 16 + (lane & 15)) * K + kt * 32 + (lane >> 4) * 8;
  bf16* dst = P + (size_t)g * 8;
#pragma unroll
  for (int j = 0; j < 8; ++j) dst[j] = (bf16)src[j];
}

// ---------------- input fc, grid-stride (+ zero sums buffer 0) ----------------

__global__ __launch_bounds__(256) void k_input_fc(
    const float* __restrict__ x, const float* __restrict__ Win,
    bf16* __restrict__ hb, float* __restrict__ sums0, int N) {
  int gid = blockIdx.x * blockDim.x + threadIdx.x;
  if (blockIdx.x == 0) { sums0[threadIdx.x] = 0.f; sums0[256 + threadIdx.x] = 0.f; }
  int total = N * HID;
  int stride = gridDim.x * blockDim.x;
  for (int idx = gid; idx < total; idx += stride) {
    int node = idx >> 8, c = idx & 255;
    float v = x[2 * node] * Win[2 * c] + x[2 * node + 1] * Win[2 * c + 1];
    hb[idx] = (bf16)v;
  }
}

// ---------------- aggregation: 2 nodes per wave, 4-deep gather ILP ----------------
// At its L3-BW roofline: 500K edges x 512B = 256MB @ ~6.3 TB/s ~= 41us. Do not touch.

__global__ __launch_bounds__(256) void k_aggregate(
    const bf16* __restrict__ hb, const int* __restrict__ offs,
    const int* __restrict__ csr, bf16* __restrict__ aggb, int N) {
  int gwave = (int)((blockIdx.x * blockDim.x + threadIdx.x) >> 6);
  int lane = threadIdx.x & 63;
  int node = gwave * 2 + (lane >> 5);
  int l32 = lane & 31;
  if (node >= N) return;
  int e0 = offs[node], e1 = offs[node + 1];
  float a[8] = {};
  int e = e0;
  for (; e + 3 < e1; e += 4) {  // 4 independent 16B gathers in flight
    int s0 = csr[e], s1 = csr[e + 1], s2 = csr[e + 2], s3 = csr[e + 3];
    bf16x8 v0 = *(const bf16x8*)(hb + (size_t)s0 * HID + l32 * 8);
    bf16x8 v1 = *(const bf16x8*)(hb + (size_t)s1 * HID + l32 * 8);
    bf16x8 v2 = *(const bf16x8*)(hb + (size_t)s2 * HID + l32 * 8);
    bf16x8 v3 = *(const bf16x8*)(hb + (size_t)s3 * HID + l32 * 8);
#pragma unroll
    for (int k = 0; k < 8; ++k)
      a[k] += ((float)v0[k] + (float)v1[k]) + ((float)v2[k] + (float)v3[k]);
  }
  for (; e < e1; ++e) {
    int s0 = csr[e];
    bf16x8 v0 = *(const bf16x8*)(hb + (size_t)s0 * HID + l32 * 8);
#pragma unroll
    for (int k = 0; k < 8; ++k) a[k] += (float)v0[k];
  }
  bf16x8 o;
#pragma unroll
  for (int k = 0; k < 8; ++k) o[k] = (bf16)a[k];
  *(bf16x8*)(aggb + (size_t)node * HID + l32 * 8) = o;
}

// ---------------- layer GEMM: out = agg@Wr^T + h@Wo^T + br, + BN stats ----------------
// Block = 64 nodes x 256 ch, operand-swapped MFMA D[ch][node]. Packed-LDS staging
// (conflict-free; LDS dedups the 4-wave B reads). SOFTWARE PIPELINE: phase-1 (hb)
// staging loads are issued into registers BEFORE phase-0 MFMA so their latency
// hides under compute. 3 barriers total.

__global__ __launch_bounds__(256) void k_layer_gemm(
    const bf16* __restrict__ aggb, const bf16* __restrict__ hb,
    const bf16* __restrict__ Pr, const bf16* __restrict__ Po,
    const float* __restrict__ bias, bf16* __restrict__ out,
    float* __restrict__ sums, int N) {
  __shared__ __align__(16) bf16 bt[32 * 64 * 8];  // 32KB packed [(kt*4+j)][lane][8]
  __shared__ float bsum[256], bsq[256];
  int tid = threadIdx.x;
  int wave = tid >> 6, lane = tid & 63;
  int l15 = lane & 15, lq = lane >> 4;
  int m0 = blockIdx.x * 64;
  f32x4 acc[4][4] = {};
  const bf16* PrW = Pr + (size_t)wave * 4 * 8 * 64 * 8;
  const bf16* PoW = Po + (size_t)wave * 4 * 8 * 64 * 8;
  int rr = tid & 63, cb = tid >> 6;  // staging: lane = row, wave = chunk-slot
  int sj = rr >> 4, sl = rr & 15;
  int gr = m0 + rr;
  bool ok = gr < N;

  // stage phase 0 (aggb) into LDS
#pragma unroll
  for (int it = 0; it < 8; ++it) {
    int c = cb + it * 4;  // 16B chunk 0..31
    bf16x8 v = {};
    if (ok) v = *(const bf16x8*)(aggb + (size_t)gr * HID + c * 8);
    *(bf16x8*)(&bt[(((c >> 2) * 4 + sj) * 64 + (c & 3) * 16 + sl) * 8]) = v;
  }
  // prefetch phase 1 (hb) into registers — latency hides under phase-0 MFMA
  bf16x8 pre[8];
#pragma unroll
  for (int it = 0; it < 8; ++it) {
    int c = cb + it * 4;
    bf16x8 v = {};
    if (ok) v = *(const bf16x8*)(hb + (size_t)gr * HID + c * 8);
    pre[it] = v;
  }
  __syncthreads();

  // phase 0 MFMA: agg @ Wr^T
  for (int kt = 0; kt < 8; ++kt) {
    bf16x8 bfr[4];
#pragma unroll
    for (int j = 0; j < 4; ++j)
      bfr[j] = *(const bf16x8*)(&bt[((kt * 4 + j) * 64 + lane) * 8]);
#pragma unroll
    for (int i = 0; i < 4; ++i) {
      bf16x8 afr = *(const bf16x8*)(PrW + ((size_t)(i * 8 + kt) * 64 + lane) * 8);
#pragma unroll
      for (int j = 0; j < 4; ++j)
        acc[i][j] = __builtin_amdgcn_mfma_f32_16x16x32_bf16(afr, bfr[j], acc[i][j], 0, 0, 0);
    }
  }
  __syncthreads();

  // commit prefetched phase-1 tile to LDS
#pragma unroll
  for (int it = 0; it < 8; ++it) {
    int c = cb + it * 4;
    *(bf16x8*)(&bt[(((c >> 2) * 4 + sj) * 64 + (c & 3) * 16 + sl) * 8]) = pre[it];
  }
  __syncthreads();

  // phase 1 MFMA: h @ Wo^T
  for (int kt = 0; kt < 8; ++kt) {
    bf16x8 bfr[4];
#pragma unroll
    for (int j = 0; j < 4; ++j)
      bfr[j] = *(const bf16x8*)(&bt[((kt * 4 + j) * 64 + lane) * 8]);
#pragma unroll
    for (int i = 0; i < 4; ++i) {
      bf16x8 afr = *(const bf16x8*)(PoW + ((size_t)(i * 8 + kt) * 64 + lane) * 8);
#pragma unroll
      for (int j = 0; j < 4; ++j)
        acc[i][j] = __builtin_amdgcn_mfma_f32_16x16x32_bf16(afr, bfr[j], acc[i][j], 0, 0, 0);
    }
  }

  // epilogue: bias, 8B stores, BN stats (in-lane j-sum + l15 butterfly)
  f32x4 bv[4];
#pragma unroll
  for (int i = 0; i < 4; ++i)
    bv[i] = *(const f32x4*)(bias + wave * 64 + i * 16 + lq * 4);
  float s[4][4] = {}, q[4][4] = {};
#pragma unroll
  for (int j = 0; j < 4; ++j) {
    int gn = m0 + j * 16 + l15;
    bool okj = gn < N;
#pragma unroll
    for (int i = 0; i < 4; ++i) {
      bf16x4 o;
#pragma unroll
      for (int r = 0; r < 4; ++r) {
        float v = acc[i][j][r] + bv[i][r];
        o[r] = (bf16)v;
        if (okj) { s[i][r] += v; q[i][r] += v * v; }
      }
      if (okj) *(bf16x4*)(out + (size_t)gn * HID + wave * 64 + i * 16 + lq * 4) = o;
    }
  }
#pragma unroll
  for (int d = 1; d < 16; d <<= 1) {
#pragma unroll
    for (int i = 0; i < 4; ++i)
#pragma unroll
      for (int r = 0; r < 4; ++r) {
        s[i][r] += __shfl_xor(s[i][r], d, 64);
        q[i][r] += __shfl_xor(q[i][r], d, 64);
      }
  }
  if (l15 == 0) {
#pragma unroll
    for (int i = 0; i < 4; ++i)
#pragma unroll
      for (int r = 0; r < 4; ++r) {
        bsum[wave * 64 + i * 16 + lq * 4 + r] = s[i][r];
        bsq[wave * 64 + i * 16 + lq * 4 + r] = q[i][r];
      }
  }
  __syncthreads();
  atomicAdd(&sums[tid], bsum[tid]);
  atomicAdd(&sums[256 + tid], bsq[tid]);
}

// ---------------- BN finalize + ReLU + residual (h kept in bf16, in place) ----------------

__global__ __launch_bounds__(256) void k_bn_residual(
    const bf16* __restrict__ outb, bf16* __restrict__ hb,
    const float* __restrict__ sums, float* __restrict__ zsums,
    const float* __restrict__ gamma, const float* __restrict__ beta,
    int N, float invN) {
  int t = threadIdx.x;
  if (blockIdx.x == 0) { zsums[t] = 0.f; zsums[256 + t] = 0.f; }
  int cg = (t & 31) * 8;
  int r0 = blockIdx.x * 32 + (t >> 5) * 4;
  float a[8], b[8];
#pragma unroll
  for (int k = 0; k < 8; ++k) {
    int c = cg + k;
    float mean = sums[c] * invN;
    float var = sums[256 + c] * invN - mean * mean;
    float istd = rsqrtf(var + 1e-5f);
    a[k] = istd * gamma[c];
    b[k] = fmaf(-mean, a[k], beta[c]);
  }
  int r1 = min(r0 + 4, N);
  for (int r = r0; r < r1; ++r) {
    size_t idx = (size_t)r * HID + cg;
    bf16x8 ov = *(const bf16x8*)(outb + idx);
    bf16x8 hv = *(const bf16x8*)(hb + idx);
    bf16x8 o;
#pragma unroll
    for (int k = 0; k < 8; ++k) {
      float y = fmaf((float)ov[k], a[k], b[k]);
      y = fmaxf(y, 0.f);
      o[k] = (bf16)((float)hv[k] + y);
    }
    *(bf16x8*)(hb + idx) = o;
  }
}

// ---------------- fused edge MLP, dst-sorted edge order (best measured: 353us) -------
// src = csr[pos], dst = edst[pos] (dst rows collapse to ~7 contiguous nodes/block);
// output scattered to original order via eperm. Per-ks staged GEMM1, packed z1f,
// GEMM2 + logit in registers.

__global__ __launch_bounds__(256) void k_edge_mlp(
    const bf16* __restrict__ hb, const int* __restrict__ csr,
    const int* __restrict__ edst, const int* __restrict__ eperm,
    const bf16* __restrict__ P1, const float* __restrict__ b1v,
    const bf16* __restrict__ P2, const float* __restrict__ b2v,
    const float* __restrict__ w3, const float* __restrict__ b3,
    float* __restrict__ outp, int E) {
  __shared__ __align__(16) bf16 asp[4 * 64 * 8];   // 4KB packed staging
  __shared__ __align__(16) bf16 z1f[32 * 64 * 8];  // 32KB packed z1
  __shared__ int nd[128];   // [0..63]=src, [64..127]=dst (sorted order)
  __shared__ int oidx[64];  // original edge id (scatter target), -1 = inactive
  __shared__ float red[64];
  int tid = threadIdx.x;
  int e0 = blockIdx.x * 64;
  if (tid < 64) {
    int p = e0 + tid;
    nd[tid] = (p < E) ? csr[p] : 0;
    oidx[tid] = (p < E) ? eperm[p] : -1;
  } else if (tid < 128) {
    int p = e0 + (tid - 64);
    nd[tid] = (p < E) ? edst[p] : 0;
  }
  if (tid < 64) red[tid] = 0.f;
  __syncthreads();
  int wave = tid >> 6, lane = tid & 63;
  int l15 = lane & 15, lq = lane >> 4;
  int sr = tid >> 2, sq = tid & 3;

  // ---- GEMM1: D[c1][e] = W1 . cat^T, K=512 ----
  f32x4 acc[4][4] = {};
  const bf16* P1W = P1 + (size_t)wave * 4 * 16 * 64 * 8;
  for (int ks = 0; ks < 16; ++ks) {
    {
      int node = nd[(ks >> 3) * 64 + sr];
      bf16x8 v = *(const bf16x8*)(hb + (size_t)node * HID + (ks & 7) * 32 + sq * 8);
      *(bf16x8*)(&asp[((sr >> 4) * 64 + sq * 16 + (sr & 15)) * 8]) = v;
    }
    __syncthreads();
    bf16x8 bfr[4];
#pragma unroll
    for (int j = 0; j < 4; ++j)
      bfr[j] = *(const bf16x8*)(&asp[(j * 64 + lane) * 8]);  // lane-sequential
#pragma unroll
    for (int i = 0; i < 4; ++i) {
      bf16x8 wf = *(const bf16x8*)(P1W + ((size_t)(i * 16 + ks) * 64 + lane) * 8);
#pragma unroll
      for (int j = 0; j < 4; ++j)
        acc[i][j] = __builtin_amdgcn_mfma_f32_16x16x32_bf16(wf, bfr[j], acc[i][j], 0, 0, 0);
    }
    __syncthreads();
  }
  // z1 -> fragment-packed LDS (8B writes, benign 2-way alias)
  {
    f32x4 b1i[4];
#pragma unroll
    for (int i = 0; i < 4; ++i)
      b1i[i] = *(const f32x4*)(b1v + wave * 64 + i * 16 + lq * 4);
#pragma unroll
    for (int j = 0; j < 4; ++j) {
#pragma unroll
      for (int i = 0; i < 4; ++i) {
        bf16x4 o;
#pragma unroll
        for (int r = 0; r < 4; ++r)
          o[r] = (bf16)fmaxf(acc[i][j][r] + b1i[i][r], 0.f);
        int kt = wave * 2 + (i >> 1);
        int slot = l15 + 16 * ((i & 1) * 2 + (lq >> 1));
        *(bf16x4*)(&z1f[((j * 8 + kt) * 64 + slot) * 8 + (lq & 1) * 4]) = o;
      }
    }
  }
  __syncthreads();

  // ---- GEMM2: D[c2][e] = W2 . z1^T, K=256 ----
  f32x4 acc2[4][4] = {};
  const bf16* P2W = P2 + (size_t)wave * 4 * 8 * 64 * 8;
  for (int ks = 0; ks < 8; ++ks) {
    bf16x8 zf[4];
#pragma unroll
    for (int j = 0; j < 4; ++j)
      zf[j] = *(const bf16x8*)(&z1f[((j * 8 + ks) * 64 + lane) * 8]);
#pragma unroll
    for (int i = 0; i < 4; ++i) {
      bf16x8 wf = *(const bf16x8*)(P2W + ((size_t)(i * 8 + ks) * 64 + lane) * 8);
#pragma unroll
      for (int j = 0; j < 4; ++j)
        acc2[i][j] = __builtin_amdgcn_mfma_f32_16x16x32_bf16(wf, zf[j], acc2[i][j], 0, 0, 0);
    }
  }

  // ---- logit = relu(z2).w3 from registers; lane col = e ----
  f32x4 b2i[4], w3i[4];
#pragma unroll
  for (int i = 0; i < 4; ++i) {
    b2i[i] = *(const f32x4*)(b2v + wave * 64 + i * 16 + lq * 4);
    w3i[i] = *(const f32x4*)(w3 + wave * 64 + i * 16 + lq * 4);
  }
  float sj2[4] = {};
#pragma unroll
  for (int j = 0; j < 4; ++j)
#pragma unroll
    for (int i = 0; i < 4; ++i)
#pragma unroll
      for (int r = 0; r < 4; ++r)
        sj2[j] = fmaf(fmaxf(acc2[i][j][r] + b2i[i][r], 0.f), w3i[i][r], sj2[j]);
#pragma unroll
  for (int j = 0; j < 4; ++j) {
    sj2[j] += __shfl_xor(sj2[j], 16, 64);
    sj2[j] += __shfl_xor(sj2[j], 32, 64);
  }
  if (lq == 0) {
#pragma unroll
    for (int j = 0; j < 4; ++j)
      atomicAdd(&red[j * 16 + l15], sj2[j]);
  }
  __syncthreads();
  if (tid < 64) {
    int oi = oidx[tid];
    if (oi >= 0) {
      float logit = red[tid] + b3[0];
      outp[oi] = 1.f / (1.f + expf(-logit));
    }
  }
}

// ---------------- host ----------------

static inline size_t align256(size_t x) { return (x + 255) & ~(size_t)255; }

extern "C" void kernel_launch(void* const* d_in, const int* in_sizes, int n_in,
                              void* d_out, int out_size, void* d_ws, size_t ws_size,
                              hipStream_t stream) {
  const float* x     = (const float*)d_in[0];
  const int*   ei    = (const int*)d_in[1];
  const float* Win   = (const float*)d_in[2];
  const float* Wrel  = (const float*)d_in[3];
  const float* brel  = (const float*)d_in[4];
  const float* Wroot = (const float*)d_in[5];
  const float* gamma = (const float*)d_in[6];
  const float* beta  = (const float*)d_in[7];
  const float* W1    = (const float*)d_in[8];
  const float* b1    = (const float*)d_in[9];
  const float* W2    = (const float*)d_in[10];
  const float* b2    = (const float*)d_in[11];
  const float* W3    = (const float*)d_in[12];
  const float* b3    = (const float*)d_in[13];

  const int N = in_sizes[0] / 2;              // 50000
  const int E = in_sizes[1] / 2;              // 500000
  const int L = in_sizes[3] / (HID * HID);    // 15

  char* p = (char*)d_ws;
  auto alloc = [&](size_t bytes) { char* r = p; p += align256(bytes); return r; };
  bf16*  hb    = (bf16*)alloc((size_t)N * HID * 2);
  bf16*  outb  = (bf16*)alloc((size_t)N * HID * 2);
  bf16*  aggb  = (bf16*)alloc((size_t)N * HID * 2);
  bf16*  Prel  = (bf16*)alloc((size_t)L * HID * HID * 2);
  bf16*  Proot = (bf16*)alloc((size_t)L * HID * HID * 2);
  bf16*  P1    = (bf16*)alloc((size_t)HID * 2 * HID * 2);
  bf16*  P2    = (bf16*)alloc((size_t)HID * HID * 2);
  int*   deg   = (int*)alloc((size_t)N * 4);
  int*   offs  = (int*)alloc((size_t)(N + 1) * 4);
  int*   cursor= (int*)alloc((size_t)N * 4);
  int*   csr   = (int*)alloc((size_t)E * 4);
  int*   edst  = (int*)alloc((size_t)E * 4);
  int*   eperm = (int*)alloc((size_t)E * 4);
  int*   bsums = (int*)alloc(64 * 4);
  float* sums  = (float*)alloc(1024 * 4);  // two ping-pong buffers of 512
  (void)ws_size; (void)n_in; (void)out_size;

  const int nb = (N + 1023) / 1024;

  // CSR build (dst-sorted edge order)
  k_zero_i32<<<(N + 255) / 256, 256, 0, stream>>>(deg, N);
  k_hist<<<(E + 255) / 256, 256, 0, stream>>>(ei, deg, E);
  k_scan1<<<nb, 1024, 0, stream>>>(deg, offs, bsums, N);
  k_scan2<<<1, 64, 0, stream>>>(bsums, nb);
  k_scan3<<<nb, 1024, 0, stream>>>(offs, cursor, bsums, N, E);
  k_fill<<<(E + 255) / 256, 256, 0, stream>>>(ei, cursor, csr, edst, eperm, E);

  // fragment-pack weights
  {
    int g1 = L * HID * HID / 8;
    k_pack<<<(g1 + 255) / 256, 256, 0, stream>>>(Wrel, Prel, HID, HID, L);
    k_pack<<<(g1 + 255) / 256, 256, 0, stream>>>(Wroot, Proot, HID, HID, L);
    int g2 = HID * 2 * HID / 8;
    k_pack<<<(g2 + 255) / 256, 256, 0, stream>>>(W1, P1, HID, 2 * HID, 1);
    int g3 = HID * HID / 8;
    k_pack<<<(g3 + 255) / 256, 256, 0, stream>>>(W2, P2, HID, HID, 1);
  }

  // input fc (+ zero sums buffer 0)
  k_input_fc<<<1024, 256, 0, stream>>>(x, Win, hb, sums, N);

  // layers: aggregate -> pipelined GEMM(+stats) -> BN+ReLU+residual
  const float invN = 1.0f / (float)N;
  for (int l = 0; l < L; ++l) {
    int sel = l & 1;
    k_aggregate<<<(N + 7) / 8, 256, 0, stream>>>(hb, offs, csr, aggb, N);
    k_layer_gemm<<<(N + 63) / 64, 256, 0, stream>>>(
        aggb, hb, Prel + (size_t)l * HID * HID, Proot + (size_t)l * HID * HID,
        brel + (size_t)l * HID, outb, sums + sel * 512, N);
    k_bn_residual<<<(N + 31) / 32, 256, 0, stream>>>(
        outb, hb, sums + sel * 512, sums + (1 - sel) * 512,
        gamma + (size_t)l * HID, beta + (size_t)l * HID, N, invN);
  }

  // edge MLP (dst-sorted order, scatter output)
  k_edge_mlp<<<(E + 63) / 64, 256, 0, stream>>>(
      hb, csr, edst, eperm, P1, b1, P2, b2, W3, b3, (float*)d_out, E);
}

// Round 12
// 1970.013 us; speedup vs baseline: 1.1710x; 1.0220x over previous
//
#include <hip/hip_runtime.h>
#include <cstdint>
#include <cstddef>

#define HID 256

typedef __bf16 bf16;
typedef __bf16 bf16x4 __attribute__((ext_vector_type(4)));
typedef __bf16 bf16x8 __attribute__((ext_vector_type(8)));
typedef float f32x4 __attribute__((ext_vector_type(4)));

// ---------------- CSR build ----------------

__global__ void k_zero_i32(int* __restrict__ p, int n) {
  int i = blockIdx.x * blockDim.x + threadIdx.x;
  if (i < n) p[i] = 0;
}

__global__ void k_hist(const int* __restrict__ ei, int* __restrict__ deg, int E) {
  int i = blockIdx.x * blockDim.x + threadIdx.x;
  if (i < E) atomicAdd(&deg[ei[E + i]], 1);  // dst = ei[E + i]
}

__global__ void k_scan1(const int* __restrict__ deg, int* __restrict__ offs,
                        int* __restrict__ bsums, int n) {
  __shared__ int sh[1024];
  int i = blockIdx.x * 1024 + threadIdx.x;
  int v = (i < n) ? deg[i] : 0;
  sh[threadIdx.x] = v;
  __syncthreads();
  for (int d = 1; d < 1024; d <<= 1) {
    int t = (threadIdx.x >= (unsigned)d) ? sh[threadIdx.x - d] : 0;
    __syncthreads();
    sh[threadIdx.x] += t;
    __syncthreads();
  }
  if (i < n) offs[i] = sh[threadIdx.x] - v;  // exclusive within block
  if (threadIdx.x == 1023) bsums[blockIdx.x] = sh[1023];
}

__global__ void k_scan2(int* __restrict__ bsums, int nb) {
  if (threadIdx.x == 0 && blockIdx.x == 0) {
    int run = 0;
    for (int b = 0; b < nb; ++b) { int t = bsums[b]; bsums[b] = run; run += t; }
  }
}

__global__ void k_scan3(int* __restrict__ offs, int* __restrict__ cursor,
                        const int* __restrict__ bsums, int n, int E) {
  int i = blockIdx.x * 1024 + threadIdx.x;
  if (i < n) { int o = offs[i] + bsums[blockIdx.x]; offs[i] = o; cursor[i] = o; }
  if (i == 0) offs[n] = E;
}

// fill CSR sorted by dst; also record dst and original edge id per slot
__global__ void k_fill(const int* __restrict__ ei, int* __restrict__ cursor,
                       int* __restrict__ csr, int* __restrict__ edst,
                       int* __restrict__ eperm, int E) {
  int i = blockIdx.x * blockDim.x + threadIdx.x;
  if (i < E) {
    int s = ei[i], d = ei[E + i];
    int pos = atomicAdd(&cursor[d], 1);
    csr[pos] = s;
    edst[pos] = d;
    eperm[pos] = i;
  }
}

// ---------------- fragment-pack weights ----------------
// P[mat][tile][kt][lane][8]: lane holds W[tile*16 + (lane&15)][kt*32 + (lane>>4)*8 + j]

__global__ void k_pack(const float* __restrict__ W, bf16* __restrict__ P,
                       int OUT, int K, int count) {
  int g = blockIdx.x * blockDim.x + threadIdx.x;
  int total = count * OUT * (K >> 3);
  if (g >= total) return;
  int lane = g & 63;
  int rest = g >> 6;
  int KT = K >> 5;
  int kt = rest % KT;
  int rest2 = rest / KT;
  int OT = OUT >> 4;
  int tile = rest2 % OT;
  int mat = rest2 / OT;
  const float* src = W + (size_t)mat * OUT * K +
                     (size_t)(tile * 16 + (lane & 15)) * K + kt * 32 + (lane >> 4) * 8;
  bf16* dst = P + (size_t)g * 8;
#pragma unroll
  for (int j = 0; j < 8; ++j) dst[j] = (bf16)src[j];
}

// ---------------- input fc, grid-stride (+ zero sums buffer 0) ----------------

__global__ __launch_bounds__(256) void k_input_fc(
    const float* __restrict__ x, const float* __restrict__ Win,
    bf16* __restrict__ hb, float* __restrict__ sums0, int N) {
  int gid = blockIdx.x * blockDim.x + threadIdx.x;
  if (blockIdx.x == 0) { sums0[threadIdx.x] = 0.f; sums0[256 + threadIdx.x] = 0.f; }
  int total = N * HID;
  int stride = gridDim.x * blockDim.x;
  for (int idx = gid; idx < total; idx += stride) {
    int node = idx >> 8, c = idx & 255;
    float v = x[2 * node] * Win[2 * c] + x[2 * node + 1] * Win[2 * c + 1];
    hb[idx] = (bf16)v;
  }
}

// ---------------- aggregation: 2 nodes per wave, 4-deep gather ILP ----------------
// At its L3-BW roofline: 500K edges x 512B = 256MB @ ~6.3 TB/s ~= 41us.

__global__ __launch_bounds__(256) void k_aggregate(
    const bf16* __restrict__ hb, const int* __restrict__ offs,
    const int* __restrict__ csr, bf16* __restrict__ aggb, int N) {
  int gwave = (int)((blockIdx.x * blockDim.x + threadIdx.x) >> 6);
  int lane = threadIdx.x & 63;
  int node = gwave * 2 + (lane >> 5);
  int l32 = lane & 31;
  if (node >= N) return;
  int e0 = offs[node], e1 = offs[node + 1];
  float a[8] = {};
  int e = e0;
  for (; e + 3 < e1; e += 4) {  // 4 independent 16B gathers in flight
    int s0 = csr[e], s1 = csr[e + 1], s2 = csr[e + 2], s3 = csr[e + 3];
    bf16x8 v0 = *(const bf16x8*)(hb + (size_t)s0 * HID + l32 * 8);
    bf16x8 v1 = *(const bf16x8*)(hb + (size_t)s1 * HID + l32 * 8);
    bf16x8 v2 = *(const bf16x8*)(hb + (size_t)s2 * HID + l32 * 8);
    bf16x8 v3 = *(const bf16x8*)(hb + (size_t)s3 * HID + l32 * 8);
#pragma unroll
    for (int k = 0; k < 8; ++k)
      a[k] += ((float)v0[k] + (float)v1[k]) + ((float)v2[k] + (float)v3[k]);
  }
  for (; e < e1; ++e) {
    int s0 = csr[e];
    bf16x8 v0 = *(const bf16x8*)(hb + (size_t)s0 * HID + l32 * 8);
#pragma unroll
    for (int k = 0; k < 8; ++k) a[k] += (float)v0[k];
  }
  bf16x8 o;
#pragma unroll
  for (int k = 0; k < 8; ++k) o[k] = (bf16)a[k];
  *(bf16x8*)(aggb + (size_t)node * HID + l32 * 8) = o;
}

// ---------------- layer GEMM (proven R9 variant): out = agg@Wr^T + h@Wo^T + br ----
// Block = 64 nodes x 256 ch, operand-swapped MFMA D[ch][node]. Packed-LDS B staging
// (LDS dedups the 4-wave B reads). 3 barriers total.

__global__ __launch_bounds__(256) void k_layer_gemm(
    const bf16* __restrict__ aggb, const bf16* __restrict__ hb,
    const bf16* __restrict__ Pr, const bf16* __restrict__ Po,
    const float* __restrict__ bias, bf16* __restrict__ out,
    float* __restrict__ sums, int N) {
  __shared__ __align__(16) bf16 bt[32 * 64 * 8];  // 32KB packed [(kt*4+j)][lane][8]
  __shared__ float bsum[256], bsq[256];
  int tid = threadIdx.x;
  int wave = tid >> 6, lane = tid & 63;
  int l15 = lane & 15, lq = lane >> 4;
  int m0 = blockIdx.x * 64;
  f32x4 acc[4][4] = {};
  const bf16* PrW = Pr + (size_t)wave * 4 * 8 * 64 * 8;
  const bf16* PoW = Po + (size_t)wave * 4 * 8 * 64 * 8;
  int rr = tid & 63, cb = tid >> 6;  // staging: lane = row, wave = chunk-slot
  int sj = rr >> 4, sl = rr & 15;

  for (int phase = 0; phase < 2; ++phase) {
    const bf16* src = phase ? hb : aggb;
    if (phase) __syncthreads();  // previous consume done before overwrite
    {
      int gr = m0 + rr;
      bool ok = gr < N;
#pragma unroll
      for (int it = 0; it < 8; ++it) {
        int c = cb + it * 4;               // 16B chunk 0..31
        bf16x8 v = {};
        if (ok) v = *(const bf16x8*)(src + (size_t)gr * HID + c * 8);
        *(bf16x8*)(&bt[(((c >> 2) * 4 + sj) * 64 + (c & 3) * 16 + sl) * 8]) = v;
      }
    }
    __syncthreads();
    const bf16* PW = phase ? PoW : PrW;
    for (int kt = 0; kt < 8; ++kt) {
      bf16x8 bfr[4];
#pragma unroll
      for (int j = 0; j < 4; ++j)
        bfr[j] = *(const bf16x8*)(&bt[((kt * 4 + j) * 64 + lane) * 8]);
#pragma unroll
      for (int i = 0; i < 4; ++i) {
        bf16x8 afr = *(const bf16x8*)(PW + ((size_t)(i * 8 + kt) * 64 + lane) * 8);
#pragma unroll
        for (int j = 0; j < 4; ++j)
          acc[i][j] = __builtin_amdgcn_mfma_f32_16x16x32_bf16(afr, bfr[j], acc[i][j], 0, 0, 0);
      }
    }
  }

  // epilogue: bias, 8B stores, BN stats (in-lane j-sum + l15 butterfly)
  f32x4 bv[4];
#pragma unroll
  for (int i = 0; i < 4; ++i)
    bv[i] = *(const f32x4*)(bias + wave * 64 + i * 16 + lq * 4);
  float s[4][4] = {}, q[4][4] = {};
#pragma unroll
  for (int j = 0; j < 4; ++j) {
    int gn = m0 + j * 16 + l15;
    bool ok = gn < N;
#pragma unroll
    for (int i = 0; i < 4; ++i) {
      bf16x4 o;
#pragma unroll
      for (int r = 0; r < 4; ++r) {
        float v = acc[i][j][r] + bv[i][r];
        o[r] = (bf16)v;
        if (ok) { s[i][r] += v; q[i][r] += v * v; }
      }
      if (ok) *(bf16x4*)(out + (size_t)gn * HID + wave * 64 + i * 16 + lq * 4) = o;
    }
  }
#pragma unroll
  for (int d = 1; d < 16; d <<= 1) {
#pragma unroll
    for (int i = 0; i < 4; ++i)
#pragma unroll
      for (int r = 0; r < 4; ++r) {
        s[i][r] += __shfl_xor(s[i][r], d, 64);
        q[i][r] += __shfl_xor(q[i][r], d, 64);
      }
  }
  if (l15 == 0) {
#pragma unroll
    for (int i = 0; i < 4; ++i)
#pragma unroll
      for (int r = 0; r < 4; ++r) {
        bsum[wave * 64 + i * 16 + lq * 4 + r] = s[i][r];
        bsq[wave * 64 + i * 16 + lq * 4 + r] = q[i][r];
      }
  }
  __syncthreads();
  atomicAdd(&sums[tid], bsum[tid]);
  atomicAdd(&sums[256 + tid], bsq[tid]);
}

// ---------------- BN finalize + ReLU + residual (h kept in bf16, in place) ----------------

__global__ __launch_bounds__(256) void k_bn_residual(
    const bf16* __restrict__ outb, bf16* __restrict__ hb,
    const float* __restrict__ sums, float* __restrict__ zsums,
    const float* __restrict__ gamma, const float* __restrict__ beta,
    int N, float invN) {
  int t = threadIdx.x;
  if (blockIdx.x == 0) { zsums[t] = 0.f; zsums[256 + t] = 0.f; }
  int cg = (t & 31) * 8;
  int r0 = blockIdx.x * 32 + (t >> 5) * 4;
  float a[8], b[8];
#pragma unroll
  for (int k = 0; k < 8; ++k) {
    int c = cg + k;
    float mean = sums[c] * invN;
    float var = sums[256 + c] * invN - mean * mean;
    float istd = rsqrtf(var + 1e-5f);
    a[k] = istd * gamma[c];
    b[k] = fmaf(-mean, a[k], beta[c]);
  }
  int r1 = min(r0 + 4, N);
  for (int r = r0; r < r1; ++r) {
    size_t idx = (size_t)r * HID + cg;
    bf16x8 ov = *(const bf16x8*)(outb + idx);
    bf16x8 hv = *(const bf16x8*)(hb + idx);
    bf16x8 o;
#pragma unroll
    for (int k = 0; k < 8; ++k) {
      float y = fmaf((float)ov[k], a[k], b[k]);
      y = fmaxf(y, 0.f);
      o[k] = (bf16)((float)hv[k] + y);
    }
    *(bf16x8*)(hb + idx) = o;
  }
}

// ---------------- fused edge MLP, dst-sorted, DOUBLE-BUFFERED staging -------
// src = csr[pos], dst = edst[pos]; output scattered via eperm. GEMM1 staging is
// double-buffered: gather for ks+1 issued before the ks MFMA block, one barrier
// per iteration (17 total vs 33) — global-load latency hides under MFMA.

__global__ __launch_bounds__(256) void k_edge_mlp(
    const bf16* __restrict__ hb, const int* __restrict__ csr,
    const int* __restrict__ edst, const int* __restrict__ eperm,
    const bf16* __restrict__ P1, const float* __restrict__ b1v,
    const bf16* __restrict__ P2, const float* __restrict__ b2v,
    const float* __restrict__ w3, const float* __restrict__ b3,
    float* __restrict__ outp, int E) {
  __shared__ __align__(16) bf16 asp[2][4 * 64 * 8];  // 2 x 4KB staging buffers
  __shared__ __align__(16) bf16 z1f[32 * 64 * 8];    // 32KB packed z1
  __shared__ int nd[128];   // [0..63]=src, [64..127]=dst (sorted order)
  __shared__ int oidx[64];  // original edge id (scatter target), -1 = inactive
  __shared__ float red[64];
  int tid = threadIdx.x;
  int e0 = blockIdx.x * 64;
  if (tid < 64) {
    int p = e0 + tid;
    nd[tid] = (p < E) ? csr[p] : 0;
    oidx[tid] = (p < E) ? eperm[p] : -1;
  } else if (tid < 128) {
    int p = e0 + (tid - 64);
    nd[tid] = (p < E) ? edst[p] : 0;
  }
  if (tid < 64) red[tid] = 0.f;
  __syncthreads();
  int wave = tid >> 6, lane = tid & 63;
  int l15 = lane & 15, lq = lane >> 4;
  int sr = tid >> 2, sq = tid & 3;
  int slot = ((sr >> 4) * 64 + sq * 16 + (sr & 15)) * 8;

  // ---- GEMM1: D[c1][e] = W1 . cat^T, K=512, double-buffered ----
  f32x4 acc[4][4] = {};
  const bf16* P1W = P1 + (size_t)wave * 4 * 16 * 64 * 8;
  {
    int node = nd[sr];
    bf16x8 v = *(const bf16x8*)(hb + (size_t)node * HID + sq * 8);
    *(bf16x8*)(&asp[0][slot]) = v;
  }
  __syncthreads();
  for (int ks = 0; ks < 16; ++ks) {
    bf16x8 vn;
    bool has = (ks + 1) < 16;
    if (has) {
      int node = nd[((ks + 1) >> 3) * 64 + sr];
      vn = *(const bf16x8*)(hb + (size_t)node * HID + ((ks + 1) & 7) * 32 + sq * 8);
    }
    const bf16* cur = asp[ks & 1];
    bf16x8 bfr[4];
#pragma unroll
    for (int j = 0; j < 4; ++j)
      bfr[j] = *(const bf16x8*)(&cur[(j * 64 + lane) * 8]);  // lane-sequential
#pragma unroll
    for (int i = 0; i < 4; ++i) {
      bf16x8 wf = *(const bf16x8*)(P1W + ((size_t)(i * 16 + ks) * 64 + lane) * 8);
#pragma unroll
      for (int j = 0; j < 4; ++j)
        acc[i][j] = __builtin_amdgcn_mfma_f32_16x16x32_bf16(wf, bfr[j], acc[i][j], 0, 0, 0);
    }
    if (has) *(bf16x8*)(&asp[(ks + 1) & 1][slot]) = vn;
    __syncthreads();
  }
  // z1 -> fragment-packed LDS (8B writes, benign 2-way alias)
  {
    f32x4 b1i[4];
#pragma unroll
    for (int i = 0; i < 4; ++i)
      b1i[i] = *(const f32x4*)(b1v + wave * 64 + i * 16 + lq * 4);
#pragma unroll
    for (int j = 0; j < 4; ++j) {
#pragma unroll
      for (int i = 0; i < 4; ++i) {
        bf16x4 o;
#pragma unroll
        for (int r = 0; r < 4; ++r)
          o[r] = (bf16)fmaxf(acc[i][j][r] + b1i[i][r], 0.f);
        int kt = wave * 2 + (i >> 1);
        int slt = l15 + 16 * ((i & 1) * 2 + (lq >> 1));
        *(bf16x4*)(&z1f[((j * 8 + kt) * 64 + slt) * 8 + (lq & 1) * 4]) = o;
      }
    }
  }
  __syncthreads();

  // ---- GEMM2: D[c2][e] = W2 . z1^T, K=256 ----
  f32x4 acc2[4][4] = {};
  const bf16* P2W = P2 + (size_t)wave * 4 * 8 * 64 * 8;
  for (int ks = 0; ks < 8; ++ks) {
    bf16x8 zf[4];
#pragma unroll
    for (int j = 0; j < 4; ++j)
      zf[j] = *(const bf16x8*)(&z1f[((j * 8 + ks) * 64 + lane) * 8]);
#pragma unroll
    for (int i = 0; i < 4; ++i) {
      bf16x8 wf = *(const bf16x8*)(P2W + ((size_t)(i * 8 + ks) * 64 + lane) * 8);
#pragma unroll
      for (int j = 0; j < 4; ++j)
        acc2[i][j] = __builtin_amdgcn_mfma_f32_16x16x32_bf16(wf, zf[j], acc2[i][j], 0, 0, 0);
    }
  }

  // ---- logit = relu(z2).w3 from registers; lane col = e ----
  f32x4 b2i[4], w3i[4];
#pragma unroll
  for (int i = 0; i < 4; ++i) {
    b2i[i] = *(const f32x4*)(b2v + wave * 64 + i * 16 + lq * 4);
    w3i[i] = *(const f32x4*)(w3 + wave * 64 + i * 16 + lq * 4);
  }
  float sj2[4] = {};
#pragma unroll
  for (int j = 0; j < 4; ++j)
#pragma unroll
    for (int i = 0; i < 4; ++i)
#pragma unroll
      for (int r = 0; r < 4; ++r)
        sj2[j] = fmaf(fmaxf(acc2[i][j][r] + b2i[i][r], 0.f), w3i[i][r], sj2[j]);
#pragma unroll
  for (int j = 0; j < 4; ++j) {
    sj2[j] += __shfl_xor(sj2[j], 16, 64);
    sj2[j] += __shfl_xor(sj2[j], 32, 64);
  }
  if (lq == 0) {
#pragma unroll
    for (int j = 0; j < 4; ++j)
      atomicAdd(&red[j * 16 + l15], sj2[j]);
  }
  __syncthreads();
  if (tid < 64) {
    int oi = oidx[tid];
    if (oi >= 0) {
      float logit = red[tid] + b3[0];
      outp[oi] = 1.f / (1.f + expf(-logit));
    }
  }
}

// ---------------- host ----------------

static inline size_t align256(size_t x) { return (x + 255) & ~(size_t)255; }

extern "C" void kernel_launch(void* const* d_in, const int* in_sizes, int n_in,
                              void* d_out, int out_size, void* d_ws, size_t ws_size,
                              hipStream_t stream) {
  const float* x     = (const float*)d_in[0];
  const int*   ei    = (const int*)d_in[1];
  const float* Win   = (const float*)d_in[2];
  const float* Wrel  = (const float*)d_in[3];
  const float* brel  = (const float*)d_in[4];
  const float* Wroot = (const float*)d_in[5];
  const float* gamma = (const float*)d_in[6];
  const float* beta  = (const float*)d_in[7];
  const float* W1    = (const float*)d_in[8];
  const float* b1    = (const float*)d_in[9];
  const float* W2    = (const float*)d_in[10];
  const float* b2    = (const float*)d_in[11];
  const float* W3    = (const float*)d_in[12];
  const float* b3    = (const float*)d_in[13];

  const int N = in_sizes[0] / 2;              // 50000
  const int E = in_sizes[1] / 2;              // 500000
  const int L = in_sizes[3] / (HID * HID);    // 15

  char* p = (char*)d_ws;
  auto alloc = [&](size_t bytes) { char* r = p; p += align256(bytes); return r; };
  bf16*  hb    = (bf16*)alloc((size_t)N * HID * 2);
  bf16*  outb  = (bf16*)alloc((size_t)N * HID * 2);
  bf16*  aggb  = (bf16*)alloc((size_t)N * HID * 2);
  bf16*  Prel  = (bf16*)alloc((size_t)L * HID * HID * 2);
  bf16*  Proot = (bf16*)alloc((size_t)L * HID * HID * 2);
  bf16*  P1    = (bf16*)alloc((size_t)HID * 2 * HID * 2);
  bf16*  P2    = (bf16*)alloc((size_t)HID * HID * 2);
  int*   deg   = (int*)alloc((size_t)N * 4);
  int*   offs  = (int*)alloc((size_t)(N + 1) * 4);
  int*   cursor= (int*)alloc((size_t)N * 4);
  int*   csr   = (int*)alloc((size_t)E * 4);
  int*   edst  = (int*)alloc((size_t)E * 4);
  int*   eperm = (int*)alloc((size_t)E * 4);
  int*   bsums = (int*)alloc(64 * 4);
  float* sums  = (float*)alloc(1024 * 4);  // two ping-pong buffers of 512
  (void)ws_size; (void)n_in; (void)out_size;

  const int nb = (N + 1023) / 1024;

  // CSR build (dst-sorted edge order)
  k_zero_i32<<<(N + 255) / 256, 256, 0, stream>>>(deg, N);
  k_hist<<<(E + 255) / 256, 256, 0, stream>>>(ei, deg, E);
  k_scan1<<<nb, 1024, 0, stream>>>(deg, offs, bsums, N);
  k_scan2<<<1, 64, 0, stream>>>(bsums, nb);
  k_scan3<<<nb, 1024, 0, stream>>>(offs, cursor, bsums, N, E);
  k_fill<<<(E + 255) / 256, 256, 0, stream>>>(ei, cursor, csr, edst, eperm, E);

  // fragment-pack weights
  {
    int g1 = L * HID * HID / 8;
    k_pack<<<(g1 + 255) / 256, 256, 0, stream>>>(Wrel, Prel, HID, HID, L);
    k_pack<<<(g1 + 255) / 256, 256, 0, stream>>>(Wroot, Proot, HID, HID, L);
    int g2 = HID * 2 * HID / 8;
    k_pack<<<(g2 + 255) / 256, 256, 0, stream>>>(W1, P1, HID, 2 * HID, 1);
    int g3 = HID * HID / 8;
    k_pack<<<(g3 + 255) / 256, 256, 0, stream>>>(W2, P2, HID, HID, 1);
  }

  // input fc (+ zero sums buffer 0)
  k_input_fc<<<1024, 256, 0, stream>>>(x, Win, hb, sums, N);

  // layers: aggregate -> GEMM(+stats) -> BN+ReLU+residual
  const float invN = 1.0f / (float)N;
  for (int l = 0; l < L; ++l) {
    int sel = l & 1;
    k_aggregate<<<(N + 7) / 8, 256, 0, stream>>>(hb, offs, csr, aggb, N);
    k_layer_gemm<<<(N + 63) / 64, 256, 0, stream>>>(
        aggb, hb, Prel + (size_t)l * HID * HID, Proot + (size_t)l * HID * HID,
        brel + (size_t)l * HID, outb, sums + sel * 512, N);
    k_bn_residual<<<(N + 31) / 32, 256, 0, stream>>>(
        outb, hb, sums + sel * 512, sums + (1 - sel) * 512,
        gamma + (size_t)l * HID, beta + (size_t)l * HID, N, invN);
  }

  // edge MLP (dst-sorted order, double-buffered staging, scatter output)
  k_edge_mlp<<<(E + 63) / 64, 256, 0, stream>>>(
      hb, csr, edst, eperm, P1, b1, P2, b2, W3, b3, (float*)d_out, E);
}

// Round 13
// 1927.877 us; speedup vs baseline: 1.1966x; 1.0219x over previous
//
#include <hip/hip_runtime.h>
#include <cstdint>
#include <cstddef>

#define HID 256

typedef __bf16 bf16;
typedef __bf16 bf16x4 __attribute__((ext_vector_type(4)));
typedef __bf16 bf16x8 __attribute__((ext_vector_type(8)));
typedef float f32x4 __attribute__((ext_vector_type(4)));

// ---------------- CSR build ----------------

__global__ void k_zero_i32(int* __restrict__ p, int n) {
  int i = blockIdx.x * blockDim.x + threadIdx.x;
  if (i < n) p[i] = 0;
}

__global__ void k_hist(const int* __restrict__ ei, int* __restrict__ deg, int E) {
  int i = blockIdx.x * blockDim.x + threadIdx.x;
  if (i < E) atomicAdd(&deg[ei[E + i]], 1);  // dst = ei[E + i]
}

__global__ void k_scan1(const int* __restrict__ deg, int* __restrict__ offs,
                        int* __restrict__ bsums, int n) {
  __shared__ int sh[1024];
  int i = blockIdx.x * 1024 + threadIdx.x;
  int v = (i < n) ? deg[i] : 0;
  sh[threadIdx.x] = v;
  __syncthreads();
  for (int d = 1; d < 1024; d <<= 1) {
    int t = (threadIdx.x >= (unsigned)d) ? sh[threadIdx.x - d] : 0;
    __syncthreads();
    sh[threadIdx.x] += t;
    __syncthreads();
  }
  if (i < n) offs[i] = sh[threadIdx.x] - v;  // exclusive within block
  if (threadIdx.x == 1023) bsums[blockIdx.x] = sh[1023];
}

__global__ void k_scan2(int* __restrict__ bsums, int nb) {
  if (threadIdx.x == 0 && blockIdx.x == 0) {
    int run = 0;
    for (int b = 0; b < nb; ++b) { int t = bsums[b]; bsums[b] = run; run += t; }
  }
}

__global__ void k_scan3(int* __restrict__ offs, int* __restrict__ cursor,
                        const int* __restrict__ bsums, int n, int E) {
  int i = blockIdx.x * 1024 + threadIdx.x;
  if (i < n) { int o = offs[i] + bsums[blockIdx.x]; offs[i] = o; cursor[i] = o; }
  if (i == 0) offs[n] = E;
}

// fill CSR sorted by dst; also record dst and original edge id per slot
__global__ void k_fill(const int* __restrict__ ei, int* __restrict__ cursor,
                       int* __restrict__ csr, int* __restrict__ edst,
                       int* __restrict__ eperm, int E) {
  int i = blockIdx.x * blockDim.x + threadIdx.x;
  if (i < E) {
    int s = ei[i], d = ei[E + i];
    int pos = atomicAdd(&cursor[d], 1);
    csr[pos] = s;
    edst[pos] = d;
    eperm[pos] = i;
  }
}

// ---------------- fragment-pack weights ----------------
// P[mat][tile][kt][lane][8]: lane holds W[tile*16 + (lane&15)][kt*32 + (lane>>4)*8 + j]

__global__ void k_pack(const float* __restrict__ W, bf16* __restrict__ P,
                       int OUT, int K, int count) {
  int g = blockIdx.x * blockDim.x + threadIdx.x;
  int total = count * OUT * (K >> 3);
  if (g >= total) return;
  int lane = g & 63;
  int rest = g >> 6;
  int KT = K >> 5;
  int kt = rest % KT;
  int rest2 = rest / KT;
  int OT = OUT >> 4;
  int tile = rest2 % OT;
  int mat = rest2 / OT;
  const float* src = W + (size_t)mat * OUT * K +
                     (size_t)(tile * 16 + (lane & 15)) * K + kt * 32 + (lane >> 4) * 8;
  bf16* dst = P + (size_t)g * 8;
#pragma unroll
  for (int j = 0; j < 8; ++j) dst[j] = (bf16)src[j];
}

// ---------------- input fc, grid-stride (+ zero sums buffer 0) ----------------

__global__ __launch_bounds__(256) void k_input_fc(
    const float* __restrict__ x, const float* __restrict__ Win,
    bf16* __restrict__ hb, float* __restrict__ sums0, int N) {
  int gid = blockIdx.x * blockDim.x + threadIdx.x;
  if (blockIdx.x == 0) { sums0[threadIdx.x] = 0.f; sums0[256 + threadIdx.x] = 0.f; }
  int total = N * HID;
  int stride = gridDim.x * blockDim.x;
  for (int idx = gid; idx < total; idx += stride) {
    int node = idx >> 8, c = idx & 255;
    float v = x[2 * node] * Win[2 * c] + x[2 * node + 1] * Win[2 * c + 1];
    hb[idx] = (bf16)v;
  }
}

// ---------------- aggregation: 2 nodes per wave, 4-deep gather ILP ----------------
// At its L3-BW roofline: 500K edges x 512B = 256MB @ ~6.2 TB/s ~= 41us.

__global__ __launch_bounds__(256) void k_aggregate(
    const bf16* __restrict__ hb, const int* __restrict__ offs,
    const int* __restrict__ csr, bf16* __restrict__ aggb, int N) {
  int gwave = (int)((blockIdx.x * blockDim.x + threadIdx.x) >> 6);
  int lane = threadIdx.x & 63;
  int node = gwave * 2 + (lane >> 5);
  int l32 = lane & 31;
  if (node >= N) return;
  int e0 = offs[node], e1 = offs[node + 1];
  float a[8] = {};
  int e = e0;
  for (; e + 3 < e1; e += 4) {  // 4 independent 16B gathers in flight
    int s0 = csr[e], s1 = csr[e + 1], s2 = csr[e + 2], s3 = csr[e + 3];
    bf16x8 v0 = *(const bf16x8*)(hb + (size_t)s0 * HID + l32 * 8);
    bf16x8 v1 = *(const bf16x8*)(hb + (size_t)s1 * HID + l32 * 8);
    bf16x8 v2 = *(const bf16x8*)(hb + (size_t)s2 * HID + l32 * 8);
    bf16x8 v3 = *(const bf16x8*)(hb + (size_t)s3 * HID + l32 * 8);
#pragma unroll
    for (int k = 0; k < 8; ++k)
      a[k] += ((float)v0[k] + (float)v1[k]) + ((float)v2[k] + (float)v3[k]);
  }
  for (; e < e1; ++e) {
    int s0 = csr[e];
    bf16x8 v0 = *(const bf16x8*)(hb + (size_t)s0 * HID + l32 * 8);
#pragma unroll
    for (int k = 0; k < 8; ++k) a[k] += (float)v0[k];
  }
  bf16x8 o;
#pragma unroll
  for (int k = 0; k < 8; ++k) o[k] = (bf16)a[k];
  *(bf16x8*)(aggb + (size_t)node * HID + l32 * 8) = o;
}

// ---------------- layer GEMM (proven R9 variant): out = agg@Wr^T + h@Wo^T + br ----
// Block = 64 nodes x 256 ch, operand-swapped MFMA D[ch][node]. Packed-LDS B staging
// (LDS dedups the 4-wave B reads). 3 barriers total.

__global__ __launch_bounds__(256) void k_layer_gemm(
    const bf16* __restrict__ aggb, const bf16* __restrict__ hb,
    const bf16* __restrict__ Pr, const bf16* __restrict__ Po,
    const float* __restrict__ bias, bf16* __restrict__ out,
    float* __restrict__ sums, int N) {
  __shared__ __align__(16) bf16 bt[32 * 64 * 8];  // 32KB packed [(kt*4+j)][lane][8]
  __shared__ float bsum[256], bsq[256];
  int tid = threadIdx.x;
  int wave = tid >> 6, lane = tid & 63;
  int l15 = lane & 15, lq = lane >> 4;
  int m0 = blockIdx.x * 64;
  f32x4 acc[4][4] = {};
  const bf16* PrW = Pr + (size_t)wave * 4 * 8 * 64 * 8;
  const bf16* PoW = Po + (size_t)wave * 4 * 8 * 64 * 8;
  int rr = tid & 63, cb = tid >> 6;  // staging: lane = row, wave = chunk-slot
  int sj = rr >> 4, sl = rr & 15;

  for (int phase = 0; phase < 2; ++phase) {
    const bf16* src = phase ? hb : aggb;
    if (phase) __syncthreads();  // previous consume done before overwrite
    {
      int gr = m0 + rr;
      bool ok = gr < N;
#pragma unroll
      for (int it = 0; it < 8; ++it) {
        int c = cb + it * 4;               // 16B chunk 0..31
        bf16x8 v = {};
        if (ok) v = *(const bf16x8*)(src + (size_t)gr * HID + c * 8);
        *(bf16x8*)(&bt[(((c >> 2) * 4 + sj) * 64 + (c & 3) * 16 + sl) * 8]) = v;
      }
    }
    __syncthreads();
    const bf16* PW = phase ? PoW : PrW;
    for (int kt = 0; kt < 8; ++kt) {
      bf16x8 bfr[4];
#pragma unroll
      for (int j = 0; j < 4; ++j)
        bfr[j] = *(const bf16x8*)(&bt[((kt * 4 + j) * 64 + lane) * 8]);
#pragma unroll
      for (int i = 0; i < 4; ++i) {
        bf16x8 afr = *(const bf16x8*)(PW + ((size_t)(i * 8 + kt) * 64 + lane) * 8);
#pragma unroll
        for (int j = 0; j < 4; ++j)
          acc[i][j] = __builtin_amdgcn_mfma_f32_16x16x32_bf16(afr, bfr[j], acc[i][j], 0, 0, 0);
      }
    }
  }

  // epilogue: bias, 8B stores, BN stats (in-lane j-sum + l15 butterfly)
  f32x4 bv[4];
#pragma unroll
  for (int i = 0; i < 4; ++i)
    bv[i] = *(const f32x4*)(bias + wave * 64 + i * 16 + lq * 4);
  float s[4][4] = {}, q[4][4] = {};
#pragma unroll
  for (int j = 0; j < 4; ++j) {
    int gn = m0 + j * 16 + l15;
    bool ok = gn < N;
#pragma unroll
    for (int i = 0; i < 4; ++i) {
      bf16x4 o;
#pragma unroll
      for (int r = 0; r < 4; ++r) {
        float v = acc[i][j][r] + bv[i][r];
        o[r] = (bf16)v;
        if (ok) { s[i][r] += v; q[i][r] += v * v; }
      }
      if (ok) *(bf16x4*)(out + (size_t)gn * HID + wave * 64 + i * 16 + lq * 4) = o;
    }
  }
#pragma unroll
  for (int d = 1; d < 16; d <<= 1) {
#pragma unroll
    for (int i = 0; i < 4; ++i)
#pragma unroll
      for (int r = 0; r < 4; ++r) {
        s[i][r] += __shfl_xor(s[i][r], d, 64);
        q[i][r] += __shfl_xor(q[i][r], d, 64);
      }
  }
  if (l15 == 0) {
#pragma unroll
    for (int i = 0; i < 4; ++i)
#pragma unroll
      for (int r = 0; r < 4; ++r) {
        bsum[wave * 64 + i * 16 + lq * 4 + r] = s[i][r];
        bsq[wave * 64 + i * 16 + lq * 4 + r] = q[i][r];
      }
  }
  __syncthreads();
  atomicAdd(&sums[tid], bsum[tid]);
  atomicAdd(&sums[256 + tid], bsq[tid]);
}

// ---------------- BN finalize + ReLU + residual (h kept in bf16, in place) ----------------

__global__ __launch_bounds__(256) void k_bn_residual(
    const bf16* __restrict__ outb, bf16* __restrict__ hb,
    const float* __restrict__ sums, float* __restrict__ zsums,
    const float* __restrict__ gamma, const float* __restrict__ beta,
    int N, float invN) {
  int t = threadIdx.x;
  if (blockIdx.x == 0) { zsums[t] = 0.f; zsums[256 + t] = 0.f; }
  int cg = (t & 31) * 8;
  int r0 = blockIdx.x * 32 + (t >> 5) * 4;
  float a[8], b[8];
#pragma unroll
  for (int k = 0; k < 8; ++k) {
    int c = cg + k;
    float mean = sums[c] * invN;
    float var = sums[256 + c] * invN - mean * mean;
    float istd = rsqrtf(var + 1e-5f);
    a[k] = istd * gamma[c];
    b[k] = fmaf(-mean, a[k], beta[c]);
  }
  int r1 = min(r0 + 4, N);
  for (int r = r0; r < r1; ++r) {
    size_t idx = (size_t)r * HID + cg;
    bf16x8 ov = *(const bf16x8*)(outb + idx);
    bf16x8 hv = *(const bf16x8*)(hb + idx);
    bf16x8 o;
#pragma unroll
    for (int k = 0; k < 8; ++k) {
      float y = fmaf((float)ov[k], a[k], b[k]);
      y = fmaxf(y, 0.f);
      o[k] = (bf16)((float)hv[k] + y);
    }
    *(bf16x8*)(hb + idx) = o;
  }
}

// ---------------- fused edge MLP: 128 edges/block, dst-sorted, dbuf staging -------
// j=8 edge-tiles per wave: each weight-fragment load feeds 8 MFMAs (2x vs before),
// halving per-edge weight L2 traffic and barrier count. Double-buffered staging
// ALIASES z1f's first 16KB (staging reads all precede z1 writes, barrier-ordered).
// LDS ~67KB -> 2 blocks/CU.

__global__ __launch_bounds__(256, 2) void k_edge_mlp(
    const bf16* __restrict__ hb, const int* __restrict__ csr,
    const int* __restrict__ edst, const int* __restrict__ eperm,
    const bf16* __restrict__ P1, const float* __restrict__ b1v,
    const bf16* __restrict__ P2, const float* __restrict__ b2v,
    const float* __restrict__ w3, const float* __restrict__ b3,
    float* __restrict__ outp, int E) {
  __shared__ __align__(16) bf16 z1f[64 * 64 * 8];  // 64KB packed z1 [(j*8+kt)][lane][8]
  __shared__ int nd[256];    // [0..127]=src, [128..255]=dst (sorted order)
  __shared__ int oidx[128];  // original edge id (scatter target), -1 = inactive
  __shared__ float red[128];
  int tid = threadIdx.x;
  int e0 = blockIdx.x * 128;
  {
    int p = e0 + (tid & 127);
    if (tid < 128) {
      nd[tid] = (p < E) ? csr[p] : 0;
      oidx[tid] = (p < E) ? eperm[p] : -1;
      red[tid] = 0.f;
    } else {
      nd[tid] = (p < E) ? edst[p] : 0;
    }
  }
  int wave = tid >> 6, lane = tid & 63;
  int l15 = lane & 15, lq = lane >> 4;
  int row = tid & 127, half = tid >> 7;   // staging: 2 threads/row, 32B each
  int sslotA = ((row >> 4) * 64 + (half * 2) * 16 + (row & 15)) * 8;
  int sslotB = ((row >> 4) * 64 + (half * 2 + 1) * 16 + (row & 15)) * 8;
  __syncthreads();

  // ---- GEMM1: D[c1][e] = W1 . cat^T, K=512, double-buffered (bufs alias z1f) ----
  f32x4 acc[4][8] = {};
  const bf16* P1W = P1 + (size_t)wave * 4 * 16 * 64 * 8;
  {
    int node = nd[row];  // ks=0 -> src half
    const bf16* rp = hb + (size_t)node * HID + half * 16;
    *(bf16x8*)(&z1f[sslotA]) = *(const bf16x8*)(rp);
    *(bf16x8*)(&z1f[sslotB]) = *(const bf16x8*)(rp + 8);
  }
  __syncthreads();
  for (int ks = 0; ks < 16; ++ks) {
    bf16x8 vn0, vn1;
    bool has = (ks + 1) < 16;
    if (has) {
      int node = nd[((ks + 1) >> 3) * 128 + row];
      const bf16* rp = hb + (size_t)node * HID + ((ks + 1) & 7) * 32 + half * 16;
      vn0 = *(const bf16x8*)(rp);
      vn1 = *(const bf16x8*)(rp + 8);
    }
    const bf16* cur = z1f + (ks & 1) * 4096;
    bf16x8 bfr[8];
#pragma unroll
    for (int j = 0; j < 8; ++j)
      bfr[j] = *(const bf16x8*)(&cur[(j * 64 + lane) * 8]);  // lane-sequential
#pragma unroll
    for (int i = 0; i < 4; ++i) {
      bf16x8 wf = *(const bf16x8*)(P1W + ((size_t)(i * 16 + ks) * 64 + lane) * 8);
#pragma unroll
      for (int j = 0; j < 8; ++j)
        acc[i][j] = __builtin_amdgcn_mfma_f32_16x16x32_bf16(wf, bfr[j], acc[i][j], 0, 0, 0);
    }
    if (has) {
      bf16* nxt = z1f + ((ks + 1) & 1) * 4096;
      *(bf16x8*)(&nxt[sslotA]) = vn0;
      *(bf16x8*)(&nxt[sslotB]) = vn1;
    }
    __syncthreads();
  }
  // z1 -> fragment-packed LDS (overwrites staging region; all reads done)
  {
    f32x4 b1i[4];
#pragma unroll
    for (int i = 0; i < 4; ++i)
      b1i[i] = *(const f32x4*)(b1v + wave * 64 + i * 16 + lq * 4);
#pragma unroll
    for (int j = 0; j < 8; ++j) {
#pragma unroll
      for (int i = 0; i < 4; ++i) {
        bf16x4 o;
#pragma unroll
        for (int r = 0; r < 4; ++r)
          o[r] = (bf16)fmaxf(acc[i][j][r] + b1i[i][r], 0.f);
        int kt = wave * 2 + (i >> 1);
        int slt = l15 + 16 * ((i & 1) * 2 + (lq >> 1));
        *(bf16x4*)(&z1f[((j * 8 + kt) * 64 + slt) * 8 + (lq & 1) * 4]) = o;
      }
    }
  }
  __syncthreads();

  // ---- GEMM2: D[c2][e] = W2 . z1^T, K=256 ----
  f32x4 acc2[4][8] = {};
  const bf16* P2W = P2 + (size_t)wave * 4 * 8 * 64 * 8;
  for (int ks = 0; ks < 8; ++ks) {
    bf16x8 zf[8];
#pragma unroll
    for (int j = 0; j < 8; ++j)
      zf[j] = *(const bf16x8*)(&z1f[((j * 8 + ks) * 64 + lane) * 8]);
#pragma unroll
    for (int i = 0; i < 4; ++i) {
      bf16x8 wf = *(const bf16x8*)(P2W + ((size_t)(i * 8 + ks) * 64 + lane) * 8);
#pragma unroll
      for (int j = 0; j < 8; ++j)
        acc2[i][j] = __builtin_amdgcn_mfma_f32_16x16x32_bf16(wf, zf[j], acc2[i][j], 0, 0, 0);
    }
  }

  // ---- logit = relu(z2).w3 from registers; lane col = e ----
  f32x4 b2i[4], w3i[4];
#pragma unroll
  for (int i = 0; i < 4; ++i) {
    b2i[i] = *(const f32x4*)(b2v + wave * 64 + i * 16 + lq * 4);
    w3i[i] = *(const f32x4*)(w3 + wave * 64 + i * 16 + lq * 4);
  }
  float sj2[8] = {};
#pragma unroll
  for (int j = 0; j < 8; ++j)
#pragma unroll
    for (int i = 0; i < 4; ++i)
#pragma unroll
      for (int r = 0; r < 4; ++r)
        sj2[j] = fmaf(fmaxf(acc2[i][j][r] + b2i[i][r], 0.f), w3i[i][r], sj2[j]);
#pragma unroll
  for (int j = 0; j < 8; ++j) {
    sj2[j] += __shfl_xor(sj2[j], 16, 64);
    sj2[j] += __shfl_xor(sj2[j], 32, 64);
  }
  if (lq == 0) {
#pragma unroll
    for (int j = 0; j < 8; ++j)
      atomicAdd(&red[j * 16 + l15], sj2[j]);
  }
  __syncthreads();
  if (tid < 128) {
    int oi = oidx[tid];
    if (oi >= 0) {
      float logit = red[tid] + b3[0];
      outp[oi] = 1.f / (1.f + expf(-logit));
    }
  }
}

// ---------------- host ----------------

static inline size_t align256(size_t x) { return (x + 255) & ~(size_t)255; }

extern "C" void kernel_launch(void* const* d_in, const int* in_sizes, int n_in,
                              void* d_out, int out_size, void* d_ws, size_t ws_size,
                              hipStream_t stream) {
  const float* x     = (const float*)d_in[0];
  const int*   ei    = (const int*)d_in[1];
  const float* Win   = (const float*)d_in[2];
  const float* Wrel  = (const float*)d_in[3];
  const float* brel  = (const float*)d_in[4];
  const float* Wroot = (const float*)d_in[5];
  const float* gamma = (const float*)d_in[6];
  const float* beta  = (const float*)d_in[7];
  const float* W1    = (const float*)d_in[8];
  const float* b1    = (const float*)d_in[9];
  const float* W2    = (const float*)d_in[10];
  const float* b2    = (const float*)d_in[11];
  const float* W3    = (const float*)d_in[12];
  const float* b3    = (const float*)d_in[13];

  const int N = in_sizes[0] / 2;              // 50000
  const int E = in_sizes[1] / 2;              // 500000
  const int L = in_sizes[3] / (HID * HID);    // 15

  char* p = (char*)d_ws;
  auto alloc = [&](size_t bytes) { char* r = p; p += align256(bytes); return r; };
  bf16*  hb    = (bf16*)alloc((size_t)N * HID * 2);
  bf16*  outb  = (bf16*)alloc((size_t)N * HID * 2);
  bf16*  aggb  = (bf16*)alloc((size_t)N * HID * 2);
  bf16*  Prel  = (bf16*)alloc((size_t)L * HID * HID * 2);
  bf16*  Proot = (bf16*)alloc((size_t)L * HID * HID * 2);
  bf16*  P1    = (bf16*)alloc((size_t)HID * 2 * HID * 2);
  bf16*  P2    = (bf16*)alloc((size_t)HID * HID * 2);
  int*   deg   = (int*)alloc((size_t)N * 4);
  int*   offs  = (int*)alloc((size_t)(N + 1) * 4);
  int*   cursor= (int*)alloc((size_t)N * 4);
  int*   csr   = (int*)alloc((size_t)E * 4);
  int*   edst  = (int*)alloc((size_t)E * 4);
  int*   eperm = (int*)alloc((size_t)E * 4);
  int*   bsums = (int*)alloc(64 * 4);
  float* sums  = (float*)alloc(1024 * 4);  // two ping-pong buffers of 512
  (void)ws_size; (void)n_in; (void)out_size;

  const int nb = (N + 1023) / 1024;

  // CSR build (dst-sorted edge order)
  k_zero_i32<<<(N + 255) / 256, 256, 0, stream>>>(deg, N);
  k_hist<<<(E + 255) / 256, 256, 0, stream>>>(ei, deg, E);
  k_scan1<<<nb, 1024, 0, stream>>>(deg, offs, bsums, N);
  k_scan2<<<1, 64, 0, stream>>>(bsums, nb);
  k_scan3<<<nb, 1024, 0, stream>>>(offs, cursor, bsums, N, E);
  k_fill<<<(E + 255) / 256, 256, 0, stream>>>(ei, cursor, csr, edst, eperm, E);

  // fragment-pack weights
  {
    int g1 = L * HID * HID / 8;
    k_pack<<<(g1 + 255) / 256, 256, 0, stream>>>(Wrel, Prel, HID, HID, L);
    k_pack<<<(g1 + 255) / 256, 256, 0, stream>>>(Wroot, Proot, HID, HID, L);
    int g2 = HID * 2 * HID / 8;
    k_pack<<<(g2 + 255) / 256, 256, 0, stream>>>(W1, P1, HID, 2 * HID, 1);
    int g3 = HID * HID / 8;
    k_pack<<<(g3 + 255) / 256, 256, 0, stream>>>(W2, P2, HID, HID, 1);
  }

  // input fc (+ zero sums buffer 0)
  k_input_fc<<<1024, 256, 0, stream>>>(x, Win, hb, sums, N);

  // layers: aggregate -> GEMM(+stats) -> BN+ReLU+residual
  const float invN = 1.0f / (float)N;
  for (int l = 0; l < L; ++l) {
    int sel = l & 1;
    k_aggregate<<<(N + 7) / 8, 256, 0, stream>>>(hb, offs, csr, aggb, N);
    k_layer_gemm<<<(N + 63) / 64, 256, 0, stream>>>(
        aggb, hb, Prel + (size_t)l * HID * HID, Proot + (size_t)l * HID * HID,
        brel + (size_t)l * HID, outb, sums + sel * 512, N);
    k_bn_residual<<<(N + 31) / 32, 256, 0, stream>>>(
        outb, hb, sums + sel * 512, sums + (1 - sel) * 512,
        gamma + (size_t)l * HID, beta + (size_t)l * HID, N, invN);
  }

  // edge MLP (128 edges/block, dst-sorted, dbuf staging, scatter output)
  k_edge_mlp<<<(E + 127) / 128, 256, 0, stream>>>(
      hb, csr, edst, eperm, P1, b1, P2, b2, W3, b3, (float*)d_out, E);
}

// Round 14
// 1798.775 us; speedup vs baseline: 1.2825x; 1.0718x over previous
//
#include <hip/hip_runtime.h>
#include <hip/hip_fp8.h>
#include <cstdint>
#include <cstddef>

#define HID 256

typedef __bf16 bf16;
typedef __bf16 bf16x4 __attribute__((ext_vector_type(4)));
typedef __bf16 bf16x8 __attribute__((ext_vector_type(8)));
typedef float f32x4 __attribute__((ext_vector_type(4)));
typedef unsigned char u8;
union f8x8 { uint2 u; u8 b[8]; };

__device__ inline u8 to_fp8(float v) {
  __hip_fp8_e4m3 t(v);
  return t.__x;
}
__device__ inline float from_fp8(u8 b) {
  __hip_fp8_e4m3 t;
  t.__x = b;
  return (float)t;
}

// ---------------- CSR build ----------------

__global__ void k_zero_i32(int* __restrict__ p, int n) {
  int i = blockIdx.x * blockDim.x + threadIdx.x;
  if (i < n) p[i] = 0;
}

__global__ void k_hist(const int* __restrict__ ei, int* __restrict__ deg, int E) {
  int i = blockIdx.x * blockDim.x + threadIdx.x;
  if (i < E) atomicAdd(&deg[ei[E + i]], 1);  // dst = ei[E + i]
}

__global__ void k_scan1(const int* __restrict__ deg, int* __restrict__ offs,
                        int* __restrict__ bsums, int n) {
  __shared__ int sh[1024];
  int i = blockIdx.x * 1024 + threadIdx.x;
  int v = (i < n) ? deg[i] : 0;
  sh[threadIdx.x] = v;
  __syncthreads();
  for (int d = 1; d < 1024; d <<= 1) {
    int t = (threadIdx.x >= (unsigned)d) ? sh[threadIdx.x - d] : 0;
    __syncthreads();
    sh[threadIdx.x] += t;
    __syncthreads();
  }
  if (i < n) offs[i] = sh[threadIdx.x] - v;  // exclusive within block
  if (threadIdx.x == 1023) bsums[blockIdx.x] = sh[1023];
}

__global__ void k_scan2(int* __restrict__ bsums, int nb) {
  if (threadIdx.x == 0 && blockIdx.x == 0) {
    int run = 0;
    for (int b = 0; b < nb; ++b) { int t = bsums[b]; bsums[b] = run; run += t; }
  }
}

__global__ void k_scan3(int* __restrict__ offs, int* __restrict__ cursor,
                        const int* __restrict__ bsums, int n, int E) {
  int i = blockIdx.x * 1024 + threadIdx.x;
  if (i < n) { int o = offs[i] + bsums[blockIdx.x]; offs[i] = o; cursor[i] = o; }
  if (i == 0) offs[n] = E;
}

// fill CSR sorted by dst; also record dst and original edge id per slot
__global__ void k_fill(const int* __restrict__ ei, int* __restrict__ cursor,
                       int* __restrict__ csr, int* __restrict__ edst,
                       int* __restrict__ eperm, int E) {
  int i = blockIdx.x * blockDim.x + threadIdx.x;
  if (i < E) {
    int s = ei[i], d = ei[E + i];
    int pos = atomicAdd(&cursor[d], 1);
    csr[pos] = s;
    edst[pos] = d;
    eperm[pos] = i;
  }
}

// ---------------- fragment-pack weights ----------------
// P[mat][tile][kt][lane][8]: lane holds W[tile*16 + (lane&15)][kt*32 + (lane>>4)*8 + j]

__global__ void k_pack(const float* __restrict__ W, bf16* __restrict__ P,
                       int OUT, int K, int count) {
  int g = blockIdx.x * blockDim.x + threadIdx.x;
  int total = count * OUT * (K >> 3);
  if (g >= total) return;
  int lane = g & 63;
  int rest = g >> 6;
  int KT = K >> 5;
  int kt = rest % KT;
  int rest2 = rest / KT;
  int OT = OUT >> 4;
  int tile = rest2 % OT;
  int mat = rest2 / OT;
  const float* src = W + (size_t)mat * OUT * K +
                     (size_t)(tile * 16 + (lane & 15)) * K + kt * 32 + (lane >> 4) * 8;
  bf16* dst = P + (size_t)g * 8;
#pragma unroll
  for (int j = 0; j < 8; ++j) dst[j] = (bf16)src[j];
}

// ---------------- input fc: writes bf16 hb AND fp8 h8 (+ zero sums buffer 0) --------

__global__ __launch_bounds__(256) void k_input_fc(
    const float* __restrict__ x, const float* __restrict__ Win,
    bf16* __restrict__ hb, u8* __restrict__ h8,
    float* __restrict__ sums0, int N) {
  if (blockIdx.x == 0) { sums0[threadIdx.x] = 0.f; sums0[256 + threadIdx.x] = 0.f; }
  int gid = blockIdx.x * blockDim.x + threadIdx.x;
  int total = N * 32;  // 8-channel chunks
  int stride = gridDim.x * blockDim.x;
  for (int idx = gid; idx < total; idx += stride) {
    int node = idx >> 5, c8 = idx & 31;
    float xa = x[2 * node], xb = x[2 * node + 1];
    bf16x8 o;
    f8x8 p;
#pragma unroll
    for (int k = 0; k < 8; ++k) {
      int c = c8 * 8 + k;
      float v = xa * Win[2 * c] + xb * Win[2 * c + 1];
      o[k] = (bf16)v;
      p.b[k] = to_fp8(v);
    }
    *(bf16x8*)(hb + (size_t)node * HID + c8 * 8) = o;
    *(uint2*)(h8 + (size_t)node * HID + c8 * 8) = p.u;
  }
}

// ---------------- aggregation: fp8 gather (128MB vs 256MB), fp32 accum, bf16 out ----
// 2 nodes per wave, 32 lanes x 8B fp8 loads, 4-deep gather ILP.

__global__ __launch_bounds__(256) void k_aggregate(
    const u8* __restrict__ h8, const int* __restrict__ offs,
    const int* __restrict__ csr, bf16* __restrict__ aggb, int N) {
  int gwave = (int)((blockIdx.x * blockDim.x + threadIdx.x) >> 6);
  int lane = threadIdx.x & 63;
  int node = gwave * 2 + (lane >> 5);
  int l32 = lane & 31;
  if (node >= N) return;
  int e0 = offs[node], e1 = offs[node + 1];
  float a[8] = {};
  int e = e0;
  for (; e + 3 < e1; e += 4) {  // 4 independent 8B gathers in flight
    int s0 = csr[e], s1 = csr[e + 1], s2 = csr[e + 2], s3 = csr[e + 3];
    f8x8 p0, p1, p2, p3;
    p0.u = *(const uint2*)(h8 + (size_t)s0 * HID + l32 * 8);
    p1.u = *(const uint2*)(h8 + (size_t)s1 * HID + l32 * 8);
    p2.u = *(const uint2*)(h8 + (size_t)s2 * HID + l32 * 8);
    p3.u = *(const uint2*)(h8 + (size_t)s3 * HID + l32 * 8);
#pragma unroll
    for (int k = 0; k < 8; ++k)
      a[k] += (from_fp8(p0.b[k]) + from_fp8(p1.b[k])) +
              (from_fp8(p2.b[k]) + from_fp8(p3.b[k]));
  }
  for (; e < e1; ++e) {
    int s0 = csr[e];
    f8x8 p0;
    p0.u = *(const uint2*)(h8 + (size_t)s0 * HID + l32 * 8);
#pragma unroll
    for (int k = 0; k < 8; ++k) a[k] += from_fp8(p0.b[k]);
  }
  bf16x8 o;
#pragma unroll
  for (int k = 0; k < 8; ++k) o[k] = (bf16)a[k];
  *(bf16x8*)(aggb + (size_t)node * HID + l32 * 8) = o;
}

// ---------------- layer GEMM (proven R9 variant): out = agg@Wr^T + h@Wo^T + br ----
// Block = 64 nodes x 256 ch, operand-swapped MFMA D[ch][node]. Packed-LDS B staging
// (LDS dedups the 4-wave B reads). 3 barriers total.

__global__ __launch_bounds__(256) void k_layer_gemm(
    const bf16* __restrict__ aggb, const bf16* __restrict__ hb,
    const bf16* __restrict__ Pr, const bf16* __restrict__ Po,
    const float* __restrict__ bias, bf16* __restrict__ out,
    float* __restrict__ sums, int N) {
  __shared__ __align__(16) bf16 bt[32 * 64 * 8];  // 32KB packed [(kt*4+j)][lane][8]
  __shared__ float bsum[256], bsq[256];
  int tid = threadIdx.x;
  int wave = tid >> 6, lane = tid & 63;
  int l15 = lane & 15, lq = lane >> 4;
  int m0 = blockIdx.x * 64;
  f32x4 acc[4][4] = {};
  const bf16* PrW = Pr + (size_t)wave * 4 * 8 * 64 * 8;
  const bf16* PoW = Po + (size_t)wave * 4 * 8 * 64 * 8;
  int rr = tid & 63, cb = tid >> 6;  // staging: lane = row, wave = chunk-slot
  int sj = rr >> 4, sl = rr & 15;

  for (int phase = 0; phase < 2; ++phase) {
    const bf16* src = phase ? hb : aggb;
    if (phase) __syncthreads();  // previous consume done before overwrite
    {
      int gr = m0 + rr;
      bool ok = gr < N;
#pragma unroll
      for (int it = 0; it < 8; ++it) {
        int c = cb + it * 4;               // 16B chunk 0..31
        bf16x8 v = {};
        if (ok) v = *(const bf16x8*)(src + (size_t)gr * HID + c * 8);
        *(bf16x8*)(&bt[(((c >> 2) * 4 + sj) * 64 + (c & 3) * 16 + sl) * 8]) = v;
      }
    }
    __syncthreads();
    const bf16* PW = phase ? PoW : PrW;
    for (int kt = 0; kt < 8; ++kt) {
      bf16x8 bfr[4];
#pragma unroll
      for (int j = 0; j < 4; ++j)
        bfr[j] = *(const bf16x8*)(&bt[((kt * 4 + j) * 64 + lane) * 8]);
#pragma unroll
      for (int i = 0; i < 4; ++i) {
        bf16x8 afr = *(const bf16x8*)(PW + ((size_t)(i * 8 + kt) * 64 + lane) * 8);
#pragma unroll
        for (int j = 0; j < 4; ++j)
          acc[i][j] = __builtin_amdgcn_mfma_f32_16x16x32_bf16(afr, bfr[j], acc[i][j], 0, 0, 0);
      }
    }
  }

  // epilogue: bias, 8B stores, BN stats (in-lane j-sum + l15 butterfly)
  f32x4 bv[4];
#pragma unroll
  for (int i = 0; i < 4; ++i)
    bv[i] = *(const f32x4*)(bias + wave * 64 + i * 16 + lq * 4);
  float s[4][4] = {}, q[4][4] = {};
#pragma unroll
  for (int j = 0; j < 4; ++j) {
    int gn = m0 + j * 16 + l15;
    bool ok = gn < N;
#pragma unroll
    for (int i = 0; i < 4; ++i) {
      bf16x4 o;
#pragma unroll
      for (int r = 0; r < 4; ++r) {
        float v = acc[i][j][r] + bv[i][r];
        o[r] = (bf16)v;
        if (ok) { s[i][r] += v; q[i][r] += v * v; }
      }
      if (ok) *(bf16x4*)(out + (size_t)gn * HID + wave * 64 + i * 16 + lq * 4) = o;
    }
  }
#pragma unroll
  for (int d = 1; d < 16; d <<= 1) {
#pragma unroll
    for (int i = 0; i < 4; ++i)
#pragma unroll
      for (int r = 0; r < 4; ++r) {
        s[i][r] += __shfl_xor(s[i][r], d, 64);
        q[i][r] += __shfl_xor(q[i][r], d, 64);
      }
  }
  if (l15 == 0) {
#pragma unroll
    for (int i = 0; i < 4; ++i)
#pragma unroll
      for (int r = 0; r < 4; ++r) {
        bsum[wave * 64 + i * 16 + lq * 4 + r] = s[i][r];
        bsq[wave * 64 + i * 16 + lq * 4 + r] = q[i][r];
      }
  }
  __syncthreads();
  atomicAdd(&sums[tid], bsum[tid]);
  atomicAdd(&sums[256 + tid], bsq[tid]);
}

// ---------------- BN finalize + ReLU + residual; writes bf16 hb AND fp8 h8 --------

__global__ __launch_bounds__(256) void k_bn_residual(
    const bf16* __restrict__ outb, bf16* __restrict__ hb, u8* __restrict__ h8,
    const float* __restrict__ sums, float* __restrict__ zsums,
    const float* __restrict__ gamma, const float* __restrict__ beta,
    int N, float invN) {
  int t = threadIdx.x;
  if (blockIdx.x == 0) { zsums[t] = 0.f; zsums[256 + t] = 0.f; }
  int cg = (t & 31) * 8;
  int r0 = blockIdx.x * 32 + (t >> 5) * 4;
  float a[8], b[8];
#pragma unroll
  for (int k = 0; k < 8; ++k) {
    int c = cg + k;
    float mean = sums[c] * invN;
    float var = sums[256 + c] * invN - mean * mean;
    float istd = rsqrtf(var + 1e-5f);
    a[k] = istd * gamma[c];
    b[k] = fmaf(-mean, a[k], beta[c]);
  }
  int r1 = min(r0 + 4, N);
  for (int r = r0; r < r1; ++r) {
    size_t idx = (size_t)r * HID + cg;
    bf16x8 ov = *(const bf16x8*)(outb + idx);
    bf16x8 hv = *(const bf16x8*)(hb + idx);
    bf16x8 o;
    f8x8 p;
#pragma unroll
    for (int k = 0; k < 8; ++k) {
      float y = fmaf((float)ov[k], a[k], b[k]);
      y = fmaxf(y, 0.f);
      float hn = (float)hv[k] + y;
      o[k] = (bf16)hn;
      p.b[k] = to_fp8(hn);
    }
    *(bf16x8*)(hb + idx) = o;
    *(uint2*)(h8 + idx) = p.u;
  }
}

// ---------------- fused edge MLP: 128 edges/block, dst-sorted, dbuf staging -------
// j=8 edge-tiles per wave; double-buffered staging ALIASES z1f's first 16KB.
// LDS ~67KB -> 2 blocks/CU. (Best measured: 288us.)

__global__ __launch_bounds__(256, 2) void k_edge_mlp(
    const bf16* __restrict__ hb, const int* __restrict__ csr,
    const int* __restrict__ edst, const int* __restrict__ eperm,
    const bf16* __restrict__ P1, const float* __restrict__ b1v,
    const bf16* __restrict__ P2, const float* __restrict__ b2v,
    const float* __restrict__ w3, const float* __restrict__ b3,
    float* __restrict__ outp, int E) {
  __shared__ __align__(16) bf16 z1f[64 * 64 * 8];  // 64KB packed z1 [(j*8+kt)][lane][8]
  __shared__ int nd[256];    // [0..127]=src, [128..255]=dst (sorted order)
  __shared__ int oidx[128];  // original edge id (scatter target), -1 = inactive
  __shared__ float red[128];
  int tid = threadIdx.x;
  int e0 = blockIdx.x * 128;
  {
    int p = e0 + (tid & 127);
    if (tid < 128) {
      nd[tid] = (p < E) ? csr[p] : 0;
      oidx[tid] = (p < E) ? eperm[p] : -1;
      red[tid] = 0.f;
    } else {
      nd[tid] = (p < E) ? edst[p] : 0;
    }
  }
  int wave = tid >> 6, lane = tid & 63;
  int l15 = lane & 15, lq = lane >> 4;
  int row = tid & 127, half = tid >> 7;   // staging: 2 threads/row, 32B each
  int sslotA = ((row >> 4) * 64 + (half * 2) * 16 + (row & 15)) * 8;
  int sslotB = ((row >> 4) * 64 + (half * 2 + 1) * 16 + (row & 15)) * 8;
  __syncthreads();

  // ---- GEMM1: D[c1][e] = W1 . cat^T, K=512, double-buffered (bufs alias z1f) ----
  f32x4 acc[4][8] = {};
  const bf16* P1W = P1 + (size_t)wave * 4 * 16 * 64 * 8;
  {
    int node = nd[row];  // ks=0 -> src half
    const bf16* rp = hb + (size_t)node * HID + half * 16;
    *(bf16x8*)(&z1f[sslotA]) = *(const bf16x8*)(rp);
    *(bf16x8*)(&z1f[sslotB]) = *(const bf16x8*)(rp + 8);
  }
  __syncthreads();
  for (int ks = 0; ks < 16; ++ks) {
    bf16x8 vn0, vn1;
    bool has = (ks + 1) < 16;
    if (has) {
      int node = nd[((ks + 1) >> 3) * 128 + row];
      const bf16* rp = hb + (size_t)node * HID + ((ks + 1) & 7) * 32 + half * 16;
      vn0 = *(const bf16x8*)(rp);
      vn1 = *(const bf16x8*)(rp + 8);
    }
    const bf16* cur = z1f + (ks & 1) * 4096;
    bf16x8 bfr[8];
#pragma unroll
    for (int j = 0; j < 8; ++j)
      bfr[j] = *(const bf16x8*)(&cur[(j * 64 + lane) * 8]);  // lane-sequential
#pragma unroll
    for (int i = 0; i < 4; ++i) {
      bf16x8 wf = *(const bf16x8*)(P1W + ((size_t)(i * 16 + ks) * 64 + lane) * 8);
#pragma unroll
      for (int j = 0; j < 8; ++j)
        acc[i][j] = __builtin_amdgcn_mfma_f32_16x16x32_bf16(wf, bfr[j], acc[i][j], 0, 0, 0);
    }
    if (has) {
      bf16* nxt = z1f + ((ks + 1) & 1) * 4096;
      *(bf16x8*)(&nxt[sslotA]) = vn0;
      *(bf16x8*)(&nxt[sslotB]) = vn1;
    }
    __syncthreads();
  }
  // z1 -> fragment-packed LDS (overwrites staging region; all reads done)
  {
    f32x4 b1i[4];
#pragma unroll
    for (int i = 0; i < 4; ++i)
      b1i[i] = *(const f32x4*)(b1v + wave * 64 + i * 16 + lq * 4);
#pragma unroll
    for (int j = 0; j < 8; ++j) {
#pragma unroll
      for (int i = 0; i < 4; ++i) {
        bf16x4 o;
#pragma unroll
        for (int r = 0; r < 4; ++r)
          o[r] = (bf16)fmaxf(acc[i][j][r] + b1i[i][r], 0.f);
        int kt = wave * 2 + (i >> 1);
        int slt = l15 + 16 * ((i & 1) * 2 + (lq >> 1));
        *(bf16x4*)(&z1f[((j * 8 + kt) * 64 + slt) * 8 + (lq & 1) * 4]) = o;
      }
    }
  }
  __syncthreads();

  // ---- GEMM2: D[c2][e] = W2 . z1^T, K=256 ----
  f32x4 acc2[4][8] = {};
  const bf16* P2W = P2 + (size_t)wave * 4 * 8 * 64 * 8;
  for (int ks = 0; ks < 8; ++ks) {
    bf16x8 zf[8];
#pragma unroll
    for (int j = 0; j < 8; ++j)
      zf[j] = *(const bf16x8*)(&z1f[((j * 8 + ks) * 64 + lane) * 8]);
#pragma unroll
    for (int i = 0; i < 4; ++i) {
      bf16x8 wf = *(const bf16x8*)(P2W + ((size_t)(i * 8 + ks) * 64 + lane) * 8);
#pragma unroll
      for (int j = 0; j < 8; ++j)
        acc2[i][j] = __builtin_amdgcn_mfma_f32_16x16x32_bf16(wf, zf[j], acc2[i][j], 0, 0, 0);
    }
  }

  // ---- logit = relu(z2).w3 from registers; lane col = e ----
  f32x4 b2i[4], w3i[4];
#pragma unroll
  for (int i = 0; i < 4; ++i) {
    b2i[i] = *(const f32x4*)(b2v + wave * 64 + i * 16 + lq * 4);
    w3i[i] = *(const f32x4*)(w3 + wave * 64 + i * 16 + lq * 4);
  }
  float sj2[8] = {};
#pragma unroll
  for (int j = 0; j < 8; ++j)
#pragma unroll
    for (int i = 0; i < 4; ++i)
#pragma unroll
      for (int r = 0; r < 4; ++r)
        sj2[j] = fmaf(fmaxf(acc2[i][j][r] + b2i[i][r], 0.f), w3i[i][r], sj2[j]);
#pragma unroll
  for (int j = 0; j < 8; ++j) {
    sj2[j] += __shfl_xor(sj2[j], 16, 64);
    sj2[j] += __shfl_xor(sj2[j], 32, 64);
  }
  if (lq == 0) {
#pragma unroll
    for (int j = 0; j < 8; ++j)
      atomicAdd(&red[j * 16 + l15], sj2[j]);
  }
  __syncthreads();
  if (tid < 128) {
    int oi = oidx[tid];
    if (oi >= 0) {
      float logit = red[tid] + b3[0];
      outp[oi] = 1.f / (1.f + expf(-logit));
    }
  }
}

// ---------------- host ----------------

static inline size_t align256(size_t x) { return (x + 255) & ~(size_t)255; }

extern "C" void kernel_launch(void* const* d_in, const int* in_sizes, int n_in,
                              void* d_out, int out_size, void* d_ws, size_t ws_size,
                              hipStream_t stream) {
  const float* x     = (const float*)d_in[0];
  const int*   ei    = (const int*)d_in[1];
  const float* Win   = (const float*)d_in[2];
  const float* Wrel  = (const float*)d_in[3];
  const float* brel  = (const float*)d_in[4];
  const float* Wroot = (const float*)d_in[5];
  const float* gamma = (const float*)d_in[6];
  const float* beta  = (const float*)d_in[7];
  const float* W1    = (const float*)d_in[8];
  const float* b1    = (const float*)d_in[9];
  const float* W2    = (const float*)d_in[10];
  const float* b2    = (const float*)d_in[11];
  const float* W3    = (const float*)d_in[12];
  const float* b3    = (const float*)d_in[13];

  const int N = in_sizes[0] / 2;              // 50000
  const int E = in_sizes[1] / 2;              // 500000
  const int L = in_sizes[3] / (HID * HID);    // 15

  char* p = (char*)d_ws;
  auto alloc = [&](size_t bytes) { char* r = p; p += align256(bytes); return r; };
  bf16*  hb    = (bf16*)alloc((size_t)N * HID * 2);
  u8*    h8    = (u8*)alloc((size_t)N * HID);
  bf16*  outb  = (bf16*)alloc((size_t)N * HID * 2);
  bf16*  aggb  = (bf16*)alloc((size_t)N * HID * 2);
  bf16*  Prel  = (bf16*)alloc((size_t)L * HID * HID * 2);
  bf16*  Proot = (bf16*)alloc((size_t)L * HID * HID * 2);
  bf16*  P1    = (bf16*)alloc((size_t)HID * 2 * HID * 2);
  bf16*  P2    = (bf16*)alloc((size_t)HID * HID * 2);
  int*   deg   = (int*)alloc((size_t)N * 4);
  int*   offs  = (int*)alloc((size_t)(N + 1) * 4);
  int*   cursor= (int*)alloc((size_t)N * 4);
  int*   csr   = (int*)alloc((size_t)E * 4);
  int*   edst  = (int*)alloc((size_t)E * 4);
  int*   eperm = (int*)alloc((size_t)E * 4);
  int*   bsums = (int*)alloc(64 * 4);
  float* sums  = (float*)alloc(1024 * 4);  // two ping-pong buffers of 512
  (void)ws_size; (void)n_in; (void)out_size;

  const int nb = (N + 1023) / 1024;

  // CSR build (dst-sorted edge order)
  k_zero_i32<<<(N + 255) / 256, 256, 0, stream>>>(deg, N);
  k_hist<<<(E + 255) / 256, 256, 0, stream>>>(ei, deg, E);
  k_scan1<<<nb, 1024, 0, stream>>>(deg, offs, bsums, N);
  k_scan2<<<1, 64, 0, stream>>>(bsums, nb);
  k_scan3<<<nb, 1024, 0, stream>>>(offs, cursor, bsums, N, E);
  k_fill<<<(E + 255) / 256, 256, 0, stream>>>(ei, cursor, csr, edst, eperm, E);

  // fragment-pack weights
  {
    int g1 = L * HID * HID / 8;
    k_pack<<<(g1 + 255) / 256, 256, 0, stream>>>(Wrel, Prel, HID, HID, L);
    k_pack<<<(g1 + 255) / 256, 256, 0, stream>>>(Wroot, Proot, HID, HID, L);
    int g2 = HID * 2 * HID / 8;
    k_pack<<<(g2 + 255) / 256, 256, 0, stream>>>(W1, P1, HID, 2 * HID, 1);
    int g3 = HID * HID / 8;
    k_pack<<<(g3 + 255) / 256, 256, 0, stream>>>(W2, P2, HID, HID, 1);
  }

  // input fc (+ zero sums buffer 0)
  k_input_fc<<<1024, 256, 0, stream>>>(x, Win, hb, h8, sums, N);

  // layers: fp8-gather aggregate -> GEMM(+stats) -> BN+ReLU+residual
  const float invN = 1.0f / (float)N;
  for (int l = 0; l < L; ++l) {
    int sel = l & 1;
    k_aggregate<<<(N + 7) / 8, 256, 0, stream>>>(h8, offs, csr, aggb, N);
    k_layer_gemm<<<(N + 63) / 64, 256, 0, stream>>>(
        aggb, hb, Prel + (size_t)l * HID * HID, Proot + (size_t)l * HID * HID,
        brel + (size_t)l * HID, outb, sums + sel * 512, N);
    k_bn_residual<<<(N + 31) / 32, 256, 0, stream>>>(
        outb, hb, h8, sums + sel * 512, sums + (1 - sel) * 512,
        gamma + (size_t)l * HID, beta + (size_t)l * HID, N, invN);
  }

  // edge MLP (128 edges/block, dst-sorted, dbuf staging, scatter output)
  k_edge_mlp<<<(E + 127) / 128, 256, 0, stream>>>(
      hb, csr, edst, eperm, P1, b1, P2, b2, W3, b3, (float*)d_out, E);
}

// Round 15
// 1594.221 us; speedup vs baseline: 1.4470x; 1.1283x over previous
//
#include <hip/hip_runtime.h>
#include <hip/hip_fp8.h>
#include <cstdint>
#include <cstddef>

#define HID 256

typedef __bf16 bf16;
typedef __bf16 bf16x4 __attribute__((ext_vector_type(4)));
typedef __bf16 bf16x8 __attribute__((ext_vector_type(8)));
typedef float f32x4 __attribute__((ext_vector_type(4)));
typedef unsigned char u8;
union f8x8 { uint2 u; u8 b[8]; };

__device__ inline u8 to_fp8(float v) {
  __hip_fp8_e4m3 t(v);
  return t.__x;
}
__device__ inline float from_fp8(u8 b) {
  __hip_fp8_e4m3 t;
  t.__x = b;
  return (float)t;
}

// ---------------- CSR build ----------------

__global__ void k_zero_i32(int* __restrict__ p, int n) {
  int i = blockIdx.x * blockDim.x + threadIdx.x;
  if (i < n) p[i] = 0;
}

__global__ void k_hist(const int* __restrict__ ei, int* __restrict__ deg, int E) {
  int i = blockIdx.x * blockDim.x + threadIdx.x;
  if (i < E) atomicAdd(&deg[ei[E + i]], 1);  // dst = ei[E + i]
}

__global__ void k_scan1(const int* __restrict__ deg, int* __restrict__ offs,
                        int* __restrict__ bsums, int n) {
  __shared__ int sh[1024];
  int i = blockIdx.x * 1024 + threadIdx.x;
  int v = (i < n) ? deg[i] : 0;
  sh[threadIdx.x] = v;
  __syncthreads();
  for (int d = 1; d < 1024; d <<= 1) {
    int t = (threadIdx.x >= (unsigned)d) ? sh[threadIdx.x - d] : 0;
    __syncthreads();
    sh[threadIdx.x] += t;
    __syncthreads();
  }
  if (i < n) offs[i] = sh[threadIdx.x] - v;  // exclusive within block
  if (threadIdx.x == 1023) bsums[blockIdx.x] = sh[1023];
}

__global__ void k_scan2(int* __restrict__ bsums, int nb) {
  if (threadIdx.x == 0 && blockIdx.x == 0) {
    int run = 0;
    for (int b = 0; b < nb; ++b) { int t = bsums[b]; bsums[b] = run; run += t; }
  }
}

__global__ void k_scan3(int* __restrict__ offs, int* __restrict__ cursor,
                        const int* __restrict__ bsums, int n, int E) {
  int i = blockIdx.x * 1024 + threadIdx.x;
  if (i < n) { int o = offs[i] + bsums[blockIdx.x]; offs[i] = o; cursor[i] = o; }
  if (i == 0) offs[n] = E;
}

// fill CSR sorted by dst; also record dst and original edge id per slot
__global__ void k_fill(const int* __restrict__ ei, int* __restrict__ cursor,
                       int* __restrict__ csr, int* __restrict__ edst,
                       int* __restrict__ eperm, int E) {
  int i = blockIdx.x * blockDim.x + threadIdx.x;
  if (i < E) {
    int s = ei[i], d = ei[E + i];
    int pos = atomicAdd(&cursor[d], 1);
    csr[pos] = s;
    edst[pos] = d;
    eperm[pos] = i;
  }
}

// ---------------- fragment-pack weights ----------------
// P[mat][tile][kt][lane][8]: lane holds W[tile*16 + (lane&15)][kt*32 + (lane>>4)*8 + j]

__global__ void k_pack(const float* __restrict__ W, bf16* __restrict__ P,
                       int OUT, int K, int count) {
  int g = blockIdx.x * blockDim.x + threadIdx.x;
  int total = count * OUT * (K >> 3);
  if (g >= total) return;
  int lane = g & 63;
  int rest = g >> 6;
  int KT = K >> 5;
  int kt = rest % KT;
  int rest2 = rest / KT;
  int OT = OUT >> 4;
  int tile = rest2 % OT;
  int mat = rest2 / OT;
  const float* src = W + (size_t)mat * OUT * K +
                     (size_t)(tile * 16 + (lane & 15)) * K + kt * 32 + (lane >> 4) * 8;
  bf16* dst = P + (size_t)g * 8;
#pragma unroll
  for (int j = 0; j < 8; ++j) dst[j] = (bf16)src[j];
}

// ---------------- input fc: writes bf16 hb AND fp8 h8 (+ zero sums buffer 0) --------

__global__ __launch_bounds__(256) void k_input_fc(
    const float* __restrict__ x, const float* __restrict__ Win,
    bf16* __restrict__ hb, u8* __restrict__ h8,
    float* __restrict__ sums0, int N) {
  if (blockIdx.x == 0) { sums0[threadIdx.x] = 0.f; sums0[256 + threadIdx.x] = 0.f; }
  int gid = blockIdx.x * blockDim.x + threadIdx.x;
  int total = N * 32;  // 8-channel chunks
  int stride = gridDim.x * blockDim.x;
  for (int idx = gid; idx < total; idx += stride) {
    int node = idx >> 5, c8 = idx & 31;
    float xa = x[2 * node], xb = x[2 * node + 1];
    bf16x8 o;
    f8x8 p;
#pragma unroll
    for (int k = 0; k < 8; ++k) {
      int c = c8 * 8 + k;
      float v = xa * Win[2 * c] + xb * Win[2 * c + 1];
      o[k] = (bf16)v;
      p.b[k] = to_fp8(v);
    }
    *(bf16x8*)(hb + (size_t)node * HID + c8 * 8) = o;
    *(uint2*)(h8 + (size_t)node * HID + c8 * 8) = p.u;
  }
}

// ---------------- aggregation: fp8 gather (128MB vs 256MB), fp32 accum, bf16 out ----
// 2 nodes per wave, 32 lanes x 8B fp8 loads, 4-deep gather ILP.

__global__ __launch_bounds__(256) void k_aggregate(
    const u8* __restrict__ h8, const int* __restrict__ offs,
    const int* __restrict__ csr, bf16* __restrict__ aggb, int N) {
  int gwave = (int)((blockIdx.x * blockDim.x + threadIdx.x) >> 6);
  int lane = threadIdx.x & 63;
  int node = gwave * 2 + (lane >> 5);
  int l32 = lane & 31;
  if (node >= N) return;
  int e0 = offs[node], e1 = offs[node + 1];
  float a[8] = {};
  int e = e0;
  for (; e + 3 < e1; e += 4) {  // 4 independent 8B gathers in flight
    int s0 = csr[e], s1 = csr[e + 1], s2 = csr[e + 2], s3 = csr[e + 3];
    f8x8 p0, p1, p2, p3;
    p0.u = *(const uint2*)(h8 + (size_t)s0 * HID + l32 * 8);
    p1.u = *(const uint2*)(h8 + (size_t)s1 * HID + l32 * 8);
    p2.u = *(const uint2*)(h8 + (size_t)s2 * HID + l32 * 8);
    p3.u = *(const uint2*)(h8 + (size_t)s3 * HID + l32 * 8);
#pragma unroll
    for (int k = 0; k < 8; ++k)
      a[k] += (from_fp8(p0.b[k]) + from_fp8(p1.b[k])) +
              (from_fp8(p2.b[k]) + from_fp8(p3.b[k]));
  }
  for (; e < e1; ++e) {
    int s0 = csr[e];
    f8x8 p0;
    p0.u = *(const uint2*)(h8 + (size_t)s0 * HID + l32 * 8);
#pragma unroll
    for (int k = 0; k < 8; ++k) a[k] += from_fp8(p0.b[k]);
  }
  bf16x8 o;
#pragma unroll
  for (int k = 0; k < 8; ++k) o[k] = (bf16)a[k];
  *(bf16x8*)(aggb + (size_t)node * HID + l32 * 8) = o;
}

// ---------------- layer GEMM: 128-node tile (j=8), out = agg@Wr^T + h@Wo^T + br ----
// Operand-swapped MFMA D[ch][node]; each weight-fragment load feeds 8 MFMAs
// (R13's edge-mlp lever applied to the layer GEMM). Packed 64KB LDS staging,
// conflict-free both directions; 2 blocks/CU. 3 barriers total.

__global__ __launch_bounds__(256, 2) void k_layer_gemm(
    const bf16* __restrict__ aggb, const bf16* __restrict__ hb,
    const bf16* __restrict__ Pr, const bf16* __restrict__ Po,
    const float* __restrict__ bias, bf16* __restrict__ out,
    float* __restrict__ sums, int N) {
  __shared__ __align__(16) bf16 bt[64 * 64 * 8];  // 64KB packed [(kt*8+j)][lane][8]
  __shared__ float bsum[256], bsq[256];
  int tid = threadIdx.x;
  int wave = tid >> 6, lane = tid & 63;
  int l15 = lane & 15, lq = lane >> 4;
  int m0 = blockIdx.x * 128;
  f32x4 acc[4][8] = {};
  const bf16* PrW = Pr + (size_t)wave * 4 * 8 * 64 * 8;
  const bf16* PoW = Po + (size_t)wave * 4 * 8 * 64 * 8;
  int row = tid & 127, half = tid >> 7;  // staging: 2 threads/row, 128ch each
  int sj = row >> 4, sl = row & 15;
  int gr = m0 + row;
  bool ok = gr < N;

  for (int phase = 0; phase < 2; ++phase) {
    const bf16* src = phase ? hb : aggb;
    if (phase) __syncthreads();  // previous consume done before overwrite
    {
#pragma unroll
      for (int i2 = 0; i2 < 16; ++i2) {
        int c = half * 16 + i2;            // 16B chunk 0..31
        bf16x8 v = {};
        if (ok) v = *(const bf16x8*)(src + (size_t)gr * HID + c * 8);
        *(bf16x8*)(&bt[(((c >> 2) * 8 + sj) * 64 + (c & 3) * 16 + sl) * 8]) = v;
      }
    }
    __syncthreads();
    const bf16* PW = phase ? PoW : PrW;
    for (int kt = 0; kt < 8; ++kt) {
      bf16x8 bfr[8];
#pragma unroll
      for (int j = 0; j < 8; ++j)
        bfr[j] = *(const bf16x8*)(&bt[((kt * 8 + j) * 64 + lane) * 8]);
#pragma unroll
      for (int i = 0; i < 4; ++i) {
        bf16x8 afr = *(const bf16x8*)(PW + ((size_t)(i * 8 + kt) * 64 + lane) * 8);
#pragma unroll
        for (int j = 0; j < 8; ++j)
          acc[i][j] = __builtin_amdgcn_mfma_f32_16x16x32_bf16(afr, bfr[j], acc[i][j], 0, 0, 0);
      }
    }
  }

  // epilogue: bias, 8B stores, BN stats (in-lane j-sum + l15 butterfly)
  f32x4 bv[4];
#pragma unroll
  for (int i = 0; i < 4; ++i)
    bv[i] = *(const f32x4*)(bias + wave * 64 + i * 16 + lq * 4);
  float s[4][4] = {}, q[4][4] = {};
#pragma unroll
  for (int j = 0; j < 8; ++j) {
    int gn = m0 + j * 16 + l15;
    bool okj = gn < N;
#pragma unroll
    for (int i = 0; i < 4; ++i) {
      bf16x4 o;
#pragma unroll
      for (int r = 0; r < 4; ++r) {
        float v = acc[i][j][r] + bv[i][r];
        o[r] = (bf16)v;
        if (okj) { s[i][r] += v; q[i][r] += v * v; }
      }
      if (okj) *(bf16x4*)(out + (size_t)gn * HID + wave * 64 + i * 16 + lq * 4) = o;
    }
  }
#pragma unroll
  for (int d = 1; d < 16; d <<= 1) {
#pragma unroll
    for (int i = 0; i < 4; ++i)
#pragma unroll
      for (int r = 0; r < 4; ++r) {
        s[i][r] += __shfl_xor(s[i][r], d, 64);
        q[i][r] += __shfl_xor(q[i][r], d, 64);
      }
  }
  if (l15 == 0) {
#pragma unroll
    for (int i = 0; i < 4; ++i)
#pragma unroll
      for (int r = 0; r < 4; ++r) {
        bsum[wave * 64 + i * 16 + lq * 4 + r] = s[i][r];
        bsq[wave * 64 + i * 16 + lq * 4 + r] = q[i][r];
      }
  }
  __syncthreads();
  atomicAdd(&sums[tid], bsum[tid]);
  atomicAdd(&sums[256 + tid], bsq[tid]);
}

// ---------------- BN finalize + ReLU + residual; writes bf16 hb AND fp8 h8 --------

__global__ __launch_bounds__(256) void k_bn_residual(
    const bf16* __restrict__ outb, bf16* __restrict__ hb, u8* __restrict__ h8,
    const float* __restrict__ sums, float* __restrict__ zsums,
    const float* __restrict__ gamma, const float* __restrict__ beta,
    int N, float invN) {
  int t = threadIdx.x;
  if (blockIdx.x == 0) { zsums[t] = 0.f; zsums[256 + t] = 0.f; }
  int cg = (t & 31) * 8;
  int r0 = blockIdx.x * 32 + (t >> 5) * 4;
  float a[8], b[8];
#pragma unroll
  for (int k = 0; k < 8; ++k) {
    int c = cg + k;
    float mean = sums[c] * invN;
    float var = sums[256 + c] * invN - mean * mean;
    float istd = rsqrtf(var + 1e-5f);
    a[k] = istd * gamma[c];
    b[k] = fmaf(-mean, a[k], beta[c]);
  }
  int r1 = min(r0 + 4, N);
  for (int r = r0; r < r1; ++r) {
    size_t idx = (size_t)r * HID + cg;
    bf16x8 ov = *(const bf16x8*)(outb + idx);
    bf16x8 hv = *(const bf16x8*)(hb + idx);
    bf16x8 o;
    f8x8 p;
#pragma unroll
    for (int k = 0; k < 8; ++k) {
      float y = fmaf((float)ov[k], a[k], b[k]);
      y = fmaxf(y, 0.f);
      float hn = (float)hv[k] + y;
      o[k] = (bf16)hn;
      p.b[k] = to_fp8(hn);
    }
    *(bf16x8*)(hb + idx) = o;
    *(uint2*)(h8 + idx) = p.u;
  }
}

// ---------------- fused edge MLP: 128 edges/block, dst-sorted, dbuf staging -------
// j=8 edge-tiles per wave; double-buffered staging ALIASES z1f's first 16KB.
// LDS ~67KB -> 2 blocks/CU. (Best measured: 276us.)

__global__ __launch_bounds__(256, 2) void k_edge_mlp(
    const bf16* __restrict__ hb, const int* __restrict__ csr,
    const int* __restrict__ edst, const int* __restrict__ eperm,
    const bf16* __restrict__ P1, const float* __restrict__ b1v,
    const bf16* __restrict__ P2, const float* __restrict__ b2v,
    const float* __restrict__ w3, const float* __restrict__ b3,
    float* __restrict__ outp, int E) {
  __shared__ __align__(16) bf16 z1f[64 * 64 * 8];  // 64KB packed z1 [(j*8+kt)][lane][8]
  __shared__ int nd[256];    // [0..127]=src, [128..255]=dst (sorted order)
  __shared__ int oidx[128];  // original edge id (scatter target), -1 = inactive
  __shared__ float red[128];
  int tid = threadIdx.x;
  int e0 = blockIdx.x * 128;
  {
    int p = e0 + (tid & 127);
    if (tid < 128) {
      nd[tid] = (p < E) ? csr[p] : 0;
      oidx[tid] = (p < E) ? eperm[p] : -1;
      red[tid] = 0.f;
    } else {
      nd[tid] = (p < E) ? edst[p] : 0;
    }
  }
  int wave = tid >> 6, lane = tid & 63;
  int l15 = lane & 15, lq = lane >> 4;
  int row = tid & 127, half = tid >> 7;   // staging: 2 threads/row, 32B each
  int sslotA = ((row >> 4) * 64 + (half * 2) * 16 + (row & 15)) * 8;
  int sslotB = ((row >> 4) * 64 + (half * 2 + 1) * 16 + (row & 15)) * 8;
  __syncthreads();

  // ---- GEMM1: D[c1][e] = W1 . cat^T, K=512, double-buffered (bufs alias z1f) ----
  f32x4 acc[4][8] = {};
  const bf16* P1W = P1 + (size_t)wave * 4 * 16 * 64 * 8;
  {
    int node = nd[row];  // ks=0 -> src half
    const bf16* rp = hb + (size_t)node * HID + half * 16;
    *(bf16x8*)(&z1f[sslotA]) = *(const bf16x8*)(rp);
    *(bf16x8*)(&z1f[sslotB]) = *(const bf16x8*)(rp + 8);
  }
  __syncthreads();
  for (int ks = 0; ks < 16; ++ks) {
    bf16x8 vn0, vn1;
    bool has = (ks + 1) < 16;
    if (has) {
      int node = nd[((ks + 1) >> 3) * 128 + row];
      const bf16* rp = hb + (size_t)node * HID + ((ks + 1) & 7) * 32 + half * 16;
      vn0 = *(const bf16x8*)(rp);
      vn1 = *(const bf16x8*)(rp + 8);
    }
    const bf16* cur = z1f + (ks & 1) * 4096;
    bf16x8 bfr[8];
#pragma unroll
    for (int j = 0; j < 8; ++j)
      bfr[j] = *(const bf16x8*)(&cur[(j * 64 + lane) * 8]);  // lane-sequential
#pragma unroll
    for (int i = 0; i < 4; ++i) {
      bf16x8 wf = *(const bf16x8*)(P1W + ((size_t)(i * 16 + ks) * 64 + lane) * 8);
#pragma unroll
      for (int j = 0; j < 8; ++j)
        acc[i][j] = __builtin_amdgcn_mfma_f32_16x16x32_bf16(wf, bfr[j], acc[i][j], 0, 0, 0);
    }
    if (has) {
      bf16* nxt = z1f + ((ks + 1) & 1) * 4096;
      *(bf16x8*)(&nxt[sslotA]) = vn0;
      *(bf16x8*)(&nxt[sslotB]) = vn1;
    }
    __syncthreads();
  }
  // z1 -> fragment-packed LDS (overwrites staging region; all reads done)
  {
    f32x4 b1i[4];
#pragma unroll
    for (int i = 0; i < 4; ++i)
      b1i[i] = *(const f32x4*)(b1v + wave * 64 + i * 16 + lq * 4);
#pragma unroll
    for (int j = 0; j < 8; ++j) {
#pragma unroll
      for (int i = 0; i < 4; ++i) {
        bf16x4 o;
#pragma unroll
        for (int r = 0; r < 4; ++r)
          o[r] = (bf16)fmaxf(acc[i][j][r] + b1i[i][r], 0.f);
        int kt = wave * 2 + (i >> 1);
        int slt = l15 + 16 * ((i & 1) * 2 + (lq >> 1));
        *(bf16x4*)(&z1f[((j * 8 + kt) * 64 + slt) * 8 + (lq & 1) * 4]) = o;
      }
    }
  }
  __syncthreads();

  // ---- GEMM2: D[c2][e] = W2 . z1^T, K=256 ----
  f32x4 acc2[4][8] = {};
  const bf16* P2W = P2 + (size_t)wave * 4 * 8 * 64 * 8;
  for (int ks = 0; ks < 8; ++ks) {
    bf16x8 zf[8];
#pragma unroll
    for (int j = 0; j < 8; ++j)
      zf[j] = *(const bf16x8*)(&z1f[((j * 8 + ks) * 64 + lane) * 8]);
#pragma unroll
    for (int i = 0; i < 4; ++i) {
      bf16x8 wf = *(const bf16x8*)(P2W + ((size_t)(i * 8 + ks) * 64 + lane) * 8);
#pragma unroll
      for (int j = 0; j < 8; ++j)
        acc2[i][j] = __builtin_amdgcn_mfma_f32_16x16x32_bf16(wf, zf[j], acc2[i][j], 0, 0, 0);
    }
  }

  // ---- logit = relu(z2).w3 from registers; lane col = e ----
  f32x4 b2i[4], w3i[4];
#pragma unroll
  for (int i = 0; i < 4; ++i) {
    b2i[i] = *(const f32x4*)(b2v + wave * 64 + i * 16 + lq * 4);
    w3i[i] = *(const f32x4*)(w3 + wave * 64 + i * 16 + lq * 4);
  }
  float sj2[8] = {};
#pragma unroll
  for (int j = 0; j < 8; ++j)
#pragma unroll
    for (int i = 0; i < 4; ++i)
#pragma unroll
      for (int r = 0; r < 4; ++r)
        sj2[j] = fmaf(fmaxf(acc2[i][j][r] + b2i[i][r], 0.f), w3i[i][r], sj2[j]);
#pragma unroll
  for (int j = 0; j < 8; ++j) {
    sj2[j] += __shfl_xor(sj2[j], 16, 64);
    sj2[j] += __shfl_xor(sj2[j], 32, 64);
  }
  if (lq == 0) {
#pragma unroll
    for (int j = 0; j < 8; ++j)
      atomicAdd(&red[j * 16 + l15], sj2[j]);
  }
  __syncthreads();
  if (tid < 128) {
    int oi = oidx[tid];
    if (oi >= 0) {
      float logit = red[tid] + b3[0];
      outp[oi] = 1.f / (1.f + expf(-logit));
    }
  }
}

// ---------------- host ----------------

static inline size_t align256(size_t x) { return (x + 255) & ~(size_t)255; }

extern "C" void kernel_launch(void* const* d_in, const int* in_sizes, int n_in,
                              void* d_out, int out_size, void* d_ws, size_t ws_size,
                              hipStream_t stream) {
  const float* x     = (const float*)d_in[0];
  const int*   ei    = (const int*)d_in[1];
  const float* Win   = (const float*)d_in[2];
  const float* Wrel  = (const float*)d_in[3];
  const float* brel  = (const float*)d_in[4];
  const float* Wroot = (const float*)d_in[5];
  const float* gamma = (const float*)d_in[6];
  const float* beta  = (const float*)d_in[7];
  const float* W1    = (const float*)d_in[8];
  const float* b1    = (const float*)d_in[9];
  const float* W2    = (const float*)d_in[10];
  const float* b2    = (const float*)d_in[11];
  const float* W3    = (const float*)d_in[12];
  const float* b3    = (const float*)d_in[13];

  const int N = in_sizes[0] / 2;              // 50000
  const int E = in_sizes[1] / 2;              // 500000
  const int L = in_sizes[3] / (HID * HID);    // 15

  char* p = (char*)d_ws;
  auto alloc = [&](size_t bytes) { char* r = p; p += align256(bytes); return r; };
  bf16*  hb    = (bf16*)alloc((size_t)N * HID * 2);
  u8*    h8    = (u8*)alloc((size_t)N * HID);
  bf16*  outb  = (bf16*)alloc((size_t)N * HID * 2);
  bf16*  aggb  = (bf16*)alloc((size_t)N * HID * 2);
  bf16*  Prel  = (bf16*)alloc((size_t)L * HID * HID * 2);
  bf16*  Proot = (bf16*)alloc((size_t)L * HID * HID * 2);
  bf16*  P1    = (bf16*)alloc((size_t)HID * 2 * HID * 2);
  bf16*  P2    = (bf16*)alloc((size_t)HID * HID * 2);
  int*   deg   = (int*)alloc((size_t)N * 4);
  int*   offs  = (int*)alloc((size_t)(N + 1) * 4);
  int*   cursor= (int*)alloc((size_t)N * 4);
  int*   csr   = (int*)alloc((size_t)E * 4);
  int*   edst  = (int*)alloc((size_t)E * 4);
  int*   eperm = (int*)alloc((size_t)E * 4);
  int*   bsums = (int*)alloc(64 * 4);
  float* sums  = (float*)alloc(1024 * 4);  // two ping-pong buffers of 512
  (void)ws_size; (void)n_in; (void)out_size;

  const int nb = (N + 1023) / 1024;

  // CSR build (dst-sorted edge order)
  k_zero_i32<<<(N + 255) / 256, 256, 0, stream>>>(deg, N);
  k_hist<<<(E + 255) / 256, 256, 0, stream>>>(ei, deg, E);
  k_scan1<<<nb, 1024, 0, stream>>>(deg, offs, bsums, N);
  k_scan2<<<1, 64, 0, stream>>>(bsums, nb);
  k_scan3<<<nb, 1024, 0, stream>>>(offs, cursor, bsums, N, E);
  k_fill<<<(E + 255) / 256, 256, 0, stream>>>(ei, cursor, csr, edst, eperm, E);

  // fragment-pack weights
  {
    int g1 = L * HID * HID / 8;
    k_pack<<<(g1 + 255) / 256, 256, 0, stream>>>(Wrel, Prel, HID, HID, L);
    k_pack<<<(g1 + 255) / 256, 256, 0, stream>>>(Wroot, Proot, HID, HID, L);
    int g2 = HID * 2 * HID / 8;
    k_pack<<<(g2 + 255) / 256, 256, 0, stream>>>(W1, P1, HID, 2 * HID, 1);
    int g3 = HID * HID / 8;
    k_pack<<<(g3 + 255) / 256, 256, 0, stream>>>(W2, P2, HID, HID, 1);
  }

  // input fc (+ zero sums buffer 0)
  k_input_fc<<<1024, 256, 0, stream>>>(x, Win, hb, h8, sums, N);

  // layers: fp8-gather aggregate -> 128-tile GEMM(+stats) -> BN+ReLU+residual
  const float invN = 1.0f / (float)N;
  for (int l = 0; l < L; ++l) {
    int sel = l & 1;
    k_aggregate<<<(N + 7) / 8, 256, 0, stream>>>(h8, offs, csr, aggb, N);
    k_layer_gemm<<<(N + 127) / 128, 256, 0, stream>>>(
        aggb, hb, Prel + (size_t)l * HID * HID, Proot + (size_t)l * HID * HID,
        brel + (size_t)l * HID, outb, sums + sel * 512, N);
    k_bn_residual<<<(N + 31) / 32, 256, 0, stream>>>(
        outb, hb, h8, sums + sel * 512, sums + (1 - sel) * 512,
        gamma + (size_t)l * HID, beta + (size_t)l * HID, N, invN);
  }

  // edge MLP (128 edges/block, dst-sorted, dbuf staging, scatter output)
  k_edge_mlp<<<(E + 127) / 128, 256, 0, stream>>>(
      hb, csr, edst, eperm, P1, b1, P2, b2, W3, b3, (float*)d_out, E);
}